// Round 1
// baseline (4333.657 us; speedup 1.0000x reference)
//
#include <hip/hip_runtime.h>

constexpr float BN_EPS = 1e-5f;

// ---------------- graph preprocessing ----------------

__global__ void hist_kernel(const int* __restrict__ src, const int* __restrict__ dst, int E,
                            int* __restrict__ cntA, int* __restrict__ cntB) {
  int e = blockIdx.x * blockDim.x + threadIdx.x;
  if (e < E) {
    atomicAdd(&cntA[src[e]], 1);   // out-degree (deg in reference)
    atomicAdd(&cntB[dst[e]], 1);   // in-degree histogram for CSR by dst
  }
}

__global__ void dis_kernel(const int* __restrict__ cnt, float* __restrict__ dis, int N) {
  int n = blockIdx.x * blockDim.x + threadIdx.x;
  if (n < N) dis[n] = cnt[n] > 0 ? rsqrtf((float)cnt[n]) : 0.f;
}

__global__ void scan1_kernel(const int* __restrict__ cnt, int N,
                             int* __restrict__ rowptr, int* __restrict__ bsums) {
  int tid = threadIdx.x, lane = tid & 63, wid = tid >> 6;
  int i = blockIdx.x * 256 + tid;
  int v = (i < N) ? cnt[i] : 0;
  int incl = v;
#pragma unroll
  for (int off = 1; off < 64; off <<= 1) {
    int u = __shfl_up(incl, off);
    if (lane >= off) incl += u;
  }
  __shared__ int wt[4];
  if (lane == 63) wt[wid] = incl;
  __syncthreads();
  int woff = 0;
  for (int w = 0; w < wid; ++w) woff += wt[w];
  if (i < N) rowptr[i] = woff + incl - v;
  if (tid == 255) bsums[blockIdx.x] = woff + incl;
}

__global__ void scan2_kernel(int* __restrict__ bsums, int NB, int* __restrict__ rowptr, int N) {
  int tid = threadIdx.x, lane = tid & 63, wid = tid >> 6;
  int v = (tid < NB) ? bsums[tid] : 0;
  int incl = v;
#pragma unroll
  for (int off = 1; off < 64; off <<= 1) {
    int u = __shfl_up(incl, off);
    if (lane >= off) incl += u;
  }
  __shared__ int wt[16];
  if (lane == 63) wt[wid] = incl;
  __syncthreads();
  int woff = 0;
  for (int w = 0; w < wid; ++w) woff += wt[w];
  if (tid < NB) bsums[tid] = woff + incl - v;
  if (tid == blockDim.x - 1) rowptr[N] = woff + incl;
}

__global__ void scan3_kernel(int* __restrict__ rowptr, const int* __restrict__ bsums, int N) {
  int i = blockIdx.x * 256 + threadIdx.x;
  if (i < N) rowptr[i] += bsums[blockIdx.x];
}

__global__ void scatter_kernel(const int* __restrict__ src, const int* __restrict__ dst, int E,
                               const int* __restrict__ rowptr, int* __restrict__ cursor,
                               const float* __restrict__ dis,
                               int* __restrict__ srcS, float* __restrict__ wS) {
  int e = blockIdx.x * blockDim.x + threadIdx.x;
  if (e < E) {
    int s = src[e], d = dst[e];
    int p = rowptr[d] + atomicAdd(&cursor[d], 1);
    srcS[p] = s;
    wS[p] = -dis[s] * dis[d];
  }
}

__global__ void pack_kernel(const float* __restrict__ x, const float* __restrict__ pos,
                            const float* __restrict__ nrm, float* __restrict__ h0, int N) {
  int idx = blockIdx.x * blockDim.x + threadIdx.x;
  if (idx < N * 16) {
    int n = idx >> 4, c = idx & 15;
    float v = 0.f;
    if (c < 3) v = x[n * 3 + c];
    else if (c < 6) v = pos[n * 3 + c - 3];
    else if (c < 9) v = nrm[n * 3 + c - 6];
    h0[idx] = v;
  }
}

// ---------------- lap: Tx1 = L_hat @ v (CSR by dst, 1 wave per NPW nodes) ----------------

template <int F>
__global__ __launch_bounds__(256) void lap_kernel(const float* __restrict__ v, float* __restrict__ out,
                                                  const int* __restrict__ rowptr,
                                                  const int* __restrict__ srcS,
                                                  const float* __restrict__ wS, int N) {
  constexpr int NPW = 64 / F;
  int tid = threadIdx.x, lane = tid & 63, wid = tid >> 6;
  int waveIdx = blockIdx.x * 4 + wid;
  int node = waveIdx * NPW + lane / F;
  int feat = lane % F;
  if (node >= N) return;
  int r0 = rowptr[node], r1 = rowptr[node + 1];
  float acc = 0.f;
  for (int k = r0; k < r1; ++k) {
    int s = srcS[k];
    acc += wS[k] * v[s * F + feat];
  }
  out[node * F + feat] = acc;
}

// ---------------- fused: T2=lap(Tx1); out = h@(W0-W2)+Tx1@W1+T2@(2W2)+b; PReLU; BN partials ----------------

template <int F_IN, int F_OUT>
__global__ __launch_bounds__(256) void cheb_kernel(
    const float* __restrict__ h, const float* __restrict__ tx1, float* __restrict__ out,
    const int* __restrict__ rowptr, const int* __restrict__ srcS, const float* __restrict__ wS,
    const float* __restrict__ W, const float* __restrict__ bias, const float* __restrict__ aP,
    float* __restrict__ partials, int N, int f_in_real) {
  __shared__ float W0m2[F_IN * F_OUT];
  __shared__ float W1s[F_IN * F_OUT];
  __shared__ float W2x2[F_IN * F_OUT];
  int tid = threadIdx.x;
  int stride = f_in_real * F_OUT;
  for (int idx = tid; idx < F_IN * F_OUT; idx += 256) {
    int i = idx / F_OUT, col = idx - i * F_OUT;
    float w0 = 0.f, w1 = 0.f, w2 = 0.f;
    if (i < f_in_real) {
      int base = i * F_OUT + col;
      w0 = W[base];
      w1 = W[stride + base];
      w2 = W[2 * stride + base];
    }
    W0m2[idx] = w0 - w2;
    W1s[idx] = w1;
    W2x2[idx] = 2.f * w2;
  }
  __syncthreads();

  float alpha = aP[0];
  int lane = tid & 63, wid = tid >> 6;
  int gw = blockIdx.x * 4 + wid;                // global wave id
  int nw = gridDim.x * 4;
  int feat = lane % F_IN;
  float ssum = 0.f, ssq = 0.f;

  for (int n = gw; n < N; n += nw) {
    float hreg = h[n * F_IN + feat];
    float t1 = tx1[n * F_IN + feat];
    float t2 = 0.f;
    int r0 = rowptr[n], r1 = rowptr[n + 1];
    for (int k = r0; k < r1; ++k) {
      int s = srcS[k];
      t2 += wS[k] * tx1[s * F_IN + feat];
    }
    float acc = 0.f;
#pragma unroll 8
    for (int i = 0; i < F_IN; ++i) {
      float hi = __shfl(hreg, i);
      float t1i = __shfl(t1, i);
      float t2i = __shfl(t2, i);
      if (lane < F_OUT)
        acc += hi * W0m2[i * F_OUT + lane] + t1i * W1s[i * F_OUT + lane] + t2i * W2x2[i * F_OUT + lane];
    }
    if (lane < F_OUT) {
      acc += bias[lane];
      acc = acc > 0.f ? acc : alpha * acc;      // PReLU
      out[n * F_OUT + lane] = acc;
      ssum += acc;
      ssq += acc * acc;
    }
  }
  if (lane < F_OUT) {
    partials[(size_t)gw * 128 + lane] = ssum;
    partials[(size_t)gw * 128 + 64 + lane] = ssq;
  }
}

// ---------------- BN stats reduce -> per-feature affine (s, t) ----------------

__global__ void stats_kernel(const float* __restrict__ partials, int nwaves,
                             const float* __restrict__ g, const float* __restrict__ be,
                             float* __restrict__ st, int F_OUT, float invN) {
  __shared__ float red[1024];
  int tid = threadIdx.x;
  int t = tid & 127, c = tid >> 7;
  float s = 0.f;
  for (int w = c; w < nwaves; w += 8) s += partials[(size_t)w * 128 + t];
  red[tid] = s;
  __syncthreads();
  if (tid < 128) {
    float tot = 0.f;
    for (int cc = 0; cc < 8; ++cc) tot += red[cc * 128 + tid];
    red[tid] = tot;
  }
  __syncthreads();
  if (tid < F_OUT) {
    float sum = red[tid], sq = red[64 + tid];
    float mu = sum * invN;
    float var = sq * invN - mu * mu;
    float sc = g[tid] * rsqrtf(var + BN_EPS);
    st[tid] = sc;
    st[64 + tid] = be[tid] - mu * sc;
  }
}

__global__ void norm_kernel(float* __restrict__ buf, const float* __restrict__ st, int total, int mask) {
  int idx = blockIdx.x * blockDim.x + threadIdx.x;
  if (idx < total) {
    int j = idx & mask;
    buf[idx] = buf[idx] * st[j] + st[64 + j];
  }
}

// ---------------- final MLP: relu(h@w1+b1) -> relu(@w2+b2) -> @w3+b3 ----------------

__global__ __launch_bounds__(256) void mlp_kernel(const float* __restrict__ h,
    const float* __restrict__ w1, const float* __restrict__ b1,
    const float* __restrict__ w2, const float* __restrict__ b2,
    const float* __restrict__ w3, const float* __restrict__ b3,
    float* __restrict__ out, int N) {
  __shared__ float W1[1024], W2[1024], W3[1024], B1[32], B2[32], B3[32];
  int tid = threadIdx.x;
  for (int idx = tid; idx < 1024; idx += 256) {
    W1[idx] = w1[idx];
    W2[idx] = w2[idx];
    W3[idx] = w3[idx];
  }
  if (tid < 32) { B1[tid] = b1[tid]; B2[tid] = b2[tid]; B3[tid] = b3[tid]; }
  __syncthreads();
  int j = tid & 31;
  int n = blockIdx.x * 8 + (tid >> 5);
  if (n >= N) return;
  float v = h[n * 32 + j];
  float a1 = B1[j];
#pragma unroll 8
  for (int i = 0; i < 32; ++i) a1 += __shfl(v, i, 32) * W1[i * 32 + j];
  a1 = fmaxf(a1, 0.f);
  float a2 = B2[j];
#pragma unroll 8
  for (int i = 0; i < 32; ++i) a2 += __shfl(a1, i, 32) * W2[i * 32 + j];
  a2 = fmaxf(a2, 0.f);
  float a3 = B3[j];
#pragma unroll 8
  for (int i = 0; i < 32; ++i) a3 += __shfl(a2, i, 32) * W3[i * 32 + j];
  out[n * 32 + j] = a3;
}

// ---------------- host ----------------

extern "C" void kernel_launch(void* const* d_in, const int* in_sizes, int n_in,
                              void* d_out, int out_size, void* d_ws, size_t ws_size,
                              hipStream_t stream) {
  const float* x   = (const float*)d_in[0];
  const float* pos = (const float*)d_in[1];
  const float* nrm = (const float*)d_in[2];
  const int*   ei  = (const int*)d_in[3];
  const float* W1p = (const float*)d_in[4];
  const float* b1p = (const float*)d_in[5];
  const float* a1p = (const float*)d_in[6];
  const float* g1p = (const float*)d_in[7];
  const float* be1p= (const float*)d_in[8];
  const float* W2p = (const float*)d_in[9];
  const float* b2p = (const float*)d_in[10];
  const float* a2p = (const float*)d_in[11];
  const float* g2p = (const float*)d_in[12];
  const float* be2p= (const float*)d_in[13];
  const float* W3p = (const float*)d_in[14];
  const float* b3p = (const float*)d_in[15];
  const float* a3p = (const float*)d_in[16];
  const float* g3p = (const float*)d_in[17];
  const float* be3p= (const float*)d_in[18];
  const float* W4p = (const float*)d_in[19];
  const float* b4p = (const float*)d_in[20];
  const float* a4p = (const float*)d_in[21];
  const float* g4p = (const float*)d_in[22];
  const float* be4p= (const float*)d_in[23];
  const float* h1w = (const float*)d_in[24];
  const float* h1b = (const float*)d_in[25];
  const float* h2w = (const float*)d_in[26];
  const float* h2b = (const float*)d_in[27];
  const float* h3w = (const float*)d_in[28];
  const float* h3b = (const float*)d_in[29];

  const int N = in_sizes[0] / 3;
  const int E = in_sizes[3] / 2;
  const int* src = ei;
  const int* dst = ei + E;

  char* p = (char*)d_ws;
  auto alloc = [&](size_t bytes) -> void* {
    void* r = (void*)p;
    p += (bytes + 255) & ~(size_t)255;
    return r;
  };
  float* dis      = (float*)alloc((size_t)N * 4);
  int*   rowptr   = (int*)  alloc((size_t)(N + 1) * 4);
  int*   cntA     = (int*)  alloc((size_t)N * 4);
  int*   cntB     = (int*)  alloc((size_t)N * 4);
  int*   bsums    = (int*)  alloc(4096 * 4);
  int*   srcS     = (int*)  alloc((size_t)E * 4);
  float* wS       = (float*)alloc((size_t)E * 4);
  float* bufA     = (float*)alloc((size_t)N * 64 * 4);
  float* bufB     = (float*)alloc((size_t)N * 64 * 4);
  float* bufC     = (float*)alloc((size_t)N * 64 * 4);
  const int CB = 768;          // cheb blocks (48KB LDS -> 3 blocks/CU)
  const int CW = CB * 4;       // cheb waves
  float* partials = (float*)alloc((size_t)CW * 128 * 4);
  float* stats    = (float*)alloc(256 * 4);

  hipMemsetAsync(cntA, 0, (size_t)N * 4, stream);
  hipMemsetAsync(cntB, 0, (size_t)N * 4, stream);
  int gE = (E + 255) / 256, gN = (N + 255) / 256;
  hist_kernel<<<gE, 256, 0, stream>>>(src, dst, E, cntA, cntB);
  dis_kernel<<<gN, 256, 0, stream>>>(cntA, dis, N);
  scan1_kernel<<<gN, 256, 0, stream>>>(cntB, N, rowptr, bsums);
  scan2_kernel<<<1, 1024, 0, stream>>>(bsums, gN, rowptr, N);
  scan3_kernel<<<gN, 256, 0, stream>>>(rowptr, bsums, N);
  hipMemsetAsync(cntB, 0, (size_t)N * 4, stream);
  scatter_kernel<<<gE, 256, 0, stream>>>(src, dst, E, rowptr, cntB, dis, srcS, wS);
  pack_kernel<<<(N * 16 + 255) / 256, 256, 0, stream>>>(x, pos, nrm, bufA, N);

  const float invN = 1.f / (float)N;

  // layer 1: 9(pad16) -> 64   h=bufA, Tx1=bufB, out=bufC
  lap_kernel<16><<<(N + 15) / 16, 256, 0, stream>>>(bufA, bufB, rowptr, srcS, wS, N);
  cheb_kernel<16, 64><<<CB, 256, 0, stream>>>(bufA, bufB, bufC, rowptr, srcS, wS, W1p, b1p, a1p, partials, N, 9);
  stats_kernel<<<1, 1024, 0, stream>>>(partials, CW, g1p, be1p, stats, 64, invN);
  norm_kernel<<<(N * 64 + 255) / 256, 256, 0, stream>>>(bufC, stats, N * 64, 63);

  // layer 2: 64 -> 64   h=bufC, Tx1=bufB, out=bufA
  lap_kernel<64><<<(N + 3) / 4, 256, 0, stream>>>(bufC, bufB, rowptr, srcS, wS, N);
  cheb_kernel<64, 64><<<CB, 256, 0, stream>>>(bufC, bufB, bufA, rowptr, srcS, wS, W2p, b2p, a2p, partials, N, 64);
  stats_kernel<<<1, 1024, 0, stream>>>(partials, CW, g2p, be2p, stats, 64, invN);
  norm_kernel<<<(N * 64 + 255) / 256, 256, 0, stream>>>(bufA, stats, N * 64, 63);

  // layer 3: 64 -> 64   h=bufA, Tx1=bufB, out=bufC
  lap_kernel<64><<<(N + 3) / 4, 256, 0, stream>>>(bufA, bufB, rowptr, srcS, wS, N);
  cheb_kernel<64, 64><<<CB, 256, 0, stream>>>(bufA, bufB, bufC, rowptr, srcS, wS, W3p, b3p, a3p, partials, N, 64);
  stats_kernel<<<1, 1024, 0, stream>>>(partials, CW, g3p, be3p, stats, 64, invN);
  norm_kernel<<<(N * 64 + 255) / 256, 256, 0, stream>>>(bufC, stats, N * 64, 63);

  // layer 4: 64 -> 32   h=bufC, Tx1=bufB, out=bufA
  lap_kernel<64><<<(N + 3) / 4, 256, 0, stream>>>(bufC, bufB, rowptr, srcS, wS, N);
  cheb_kernel<64, 32><<<CB, 256, 0, stream>>>(bufC, bufB, bufA, rowptr, srcS, wS, W4p, b4p, a4p, partials, N, 64);
  stats_kernel<<<1, 1024, 0, stream>>>(partials, CW, g4p, be4p, stats, 32, invN);
  norm_kernel<<<(N * 32 + 255) / 256, 256, 0, stream>>>(bufA, stats, N * 32, 31);

  // final MLP
  mlp_kernel<<<(N + 7) / 8, 256, 0, stream>>>(bufA, h1w, h1b, h2w, h2b, h3w, h3b, (float*)d_out, N);
}

// Round 2
// 2254.484 us; speedup vs baseline: 1.9222x; 1.9222x over previous
//
#include <hip/hip_runtime.h>

constexpr float BN_EPS = 1e-5f;

// ---------------- graph preprocessing ----------------

__global__ void hist_kernel(const int* __restrict__ src, const int* __restrict__ dst, int E,
                            int* __restrict__ cntA, int* __restrict__ cntB) {
  int e = blockIdx.x * blockDim.x + threadIdx.x;
  if (e < E) {
    atomicAdd(&cntA[src[e]], 1);   // out-degree (deg in reference)
    atomicAdd(&cntB[dst[e]], 1);   // in-degree histogram for CSR by dst
  }
}

__global__ void dis_kernel(const int* __restrict__ cnt, float* __restrict__ dis, int N) {
  int n = blockIdx.x * blockDim.x + threadIdx.x;
  if (n < N) dis[n] = cnt[n] > 0 ? rsqrtf((float)cnt[n]) : 0.f;
}

__global__ void scan1_kernel(const int* __restrict__ cnt, int N,
                             int* __restrict__ rowptr, int* __restrict__ bsums) {
  int tid = threadIdx.x, lane = tid & 63, wid = tid >> 6;
  int i = blockIdx.x * 256 + tid;
  int v = (i < N) ? cnt[i] : 0;
  int incl = v;
#pragma unroll
  for (int off = 1; off < 64; off <<= 1) {
    int u = __shfl_up(incl, off);
    if (lane >= off) incl += u;
  }
  __shared__ int wt[4];
  if (lane == 63) wt[wid] = incl;
  __syncthreads();
  int woff = 0;
  for (int w = 0; w < wid; ++w) woff += wt[w];
  if (i < N) rowptr[i] = woff + incl - v;
  if (tid == 255) bsums[blockIdx.x] = woff + incl;
}

__global__ void scan2_kernel(int* __restrict__ bsums, int NB, int* __restrict__ rowptr, int N) {
  int tid = threadIdx.x, lane = tid & 63, wid = tid >> 6;
  int v = (tid < NB) ? bsums[tid] : 0;
  int incl = v;
#pragma unroll
  for (int off = 1; off < 64; off <<= 1) {
    int u = __shfl_up(incl, off);
    if (lane >= off) incl += u;
  }
  __shared__ int wt[16];
  if (lane == 63) wt[wid] = incl;
  __syncthreads();
  int woff = 0;
  for (int w = 0; w < wid; ++w) woff += wt[w];
  if (tid < NB) bsums[tid] = woff + incl - v;
  if (tid == blockDim.x - 1) rowptr[N] = woff + incl;
}

__global__ void scan3_kernel(int* __restrict__ rowptr, const int* __restrict__ bsums, int N) {
  int i = blockIdx.x * 256 + threadIdx.x;
  if (i < N) rowptr[i] += bsums[blockIdx.x];
}

__global__ void scatter_kernel(const int* __restrict__ src, const int* __restrict__ dst, int E,
                               const int* __restrict__ rowptr, int* __restrict__ cursor,
                               const float* __restrict__ dis,
                               int* __restrict__ srcS, float* __restrict__ wS) {
  int e = blockIdx.x * blockDim.x + threadIdx.x;
  if (e < E) {
    int s = src[e], d = dst[e];
    int p = rowptr[d] + atomicAdd(&cursor[d], 1);
    srcS[p] = s;
    wS[p] = -dis[s] * dis[d];
  }
}

__global__ void pack_kernel(const float* __restrict__ x, const float* __restrict__ pos,
                            const float* __restrict__ nrm, float* __restrict__ h0, int N) {
  int idx = blockIdx.x * blockDim.x + threadIdx.x;
  if (idx < N * 16) {
    int n = idx >> 4, c = idx & 15;
    float v = 0.f;
    if (c < 3) v = x[n * 3 + c];
    else if (c < 6) v = pos[n * 3 + c - 3];
    else if (c < 9) v = nrm[n * 3 + c - 6];
    h0[idx] = v;
  }
}

// ---------------- lap (vectorized): out = L_hat @ v ----------------
// F=64: one node per wave; lanes = 4 edge-slots x 16 float4

__global__ __launch_bounds__(256) void lap64_kernel(const float4* __restrict__ v, float4* __restrict__ out,
                                                    const int* __restrict__ rowptr,
                                                    const int* __restrict__ srcS,
                                                    const float* __restrict__ wS, int N) {
  int tid = threadIdx.x, lane = tid & 63, wid = tid >> 6;
  int node = blockIdx.x * 4 + wid;
  if (node >= N) return;
  int g = lane >> 4, q = lane & 15;
  int r0 = rowptr[node], r1 = rowptr[node + 1];
  float4 acc = {0.f, 0.f, 0.f, 0.f}, acc2 = {0.f, 0.f, 0.f, 0.f};
  int k = r0 + g;
  for (; k + 4 < r1; k += 8) {
    int s0 = srcS[k];     float w0 = wS[k];     float4 t0 = v[s0 * 16 + q];
    int s1 = srcS[k + 4]; float w1 = wS[k + 4]; float4 t1 = v[s1 * 16 + q];
    acc.x  += w0 * t0.x; acc.y  += w0 * t0.y; acc.z  += w0 * t0.z; acc.w  += w0 * t0.w;
    acc2.x += w1 * t1.x; acc2.y += w1 * t1.y; acc2.z += w1 * t1.z; acc2.w += w1 * t1.w;
  }
  if (k < r1) {
    int s = srcS[k]; float w = wS[k]; float4 t = v[s * 16 + q];
    acc.x += w * t.x; acc.y += w * t.y; acc.z += w * t.z; acc.w += w * t.w;
  }
  acc.x += acc2.x; acc.y += acc2.y; acc.z += acc2.z; acc.w += acc2.w;
  acc.x += __shfl_xor(acc.x, 16); acc.y += __shfl_xor(acc.y, 16);
  acc.z += __shfl_xor(acc.z, 16); acc.w += __shfl_xor(acc.w, 16);
  acc.x += __shfl_xor(acc.x, 32); acc.y += __shfl_xor(acc.y, 32);
  acc.z += __shfl_xor(acc.z, 32); acc.w += __shfl_xor(acc.w, 32);
  if (g == 0) out[node * 16 + q] = acc;
}

// F=16: 4 nodes per wave; per node 16 lanes = 4 edge-slots x 4 float4

__global__ __launch_bounds__(256) void lap16_kernel(const float4* __restrict__ v, float4* __restrict__ out,
                                                    const int* __restrict__ rowptr,
                                                    const int* __restrict__ srcS,
                                                    const float* __restrict__ wS, int N) {
  int tid = threadIdx.x, lane = tid & 63, wid = tid >> 6;
  int node = (blockIdx.x * 4 + wid) * 4 + (lane >> 4);
  int sub = lane & 15, g = sub >> 2, q = sub & 3;
  float4 acc = {0.f, 0.f, 0.f, 0.f};
  if (node < N) {
    int r0 = rowptr[node], r1 = rowptr[node + 1];
    for (int k = r0 + g; k < r1; k += 4) {
      int s = srcS[k]; float w = wS[k]; float4 t = v[s * 4 + q];
      acc.x += w * t.x; acc.y += w * t.y; acc.z += w * t.z; acc.w += w * t.w;
    }
  }
  acc.x += __shfl_xor(acc.x, 4); acc.y += __shfl_xor(acc.y, 4);
  acc.z += __shfl_xor(acc.z, 4); acc.w += __shfl_xor(acc.w, 4);
  acc.x += __shfl_xor(acc.x, 8); acc.y += __shfl_xor(acc.y, 8);
  acc.z += __shfl_xor(acc.z, 8); acc.w += __shfl_xor(acc.w, 8);
  if (node < N && g == 0) out[node * 4 + q] = acc;
}

// ---------------- streaming matmul: out = h@(W0-W2)+t1@W1+t2@(2W2)+b; PReLU; BN partials ----------------
// NOTE: out may alias h (node-local read-before-write within one wave) -> no __restrict__ on h/out.

template <int F_IN, int F_OUT>
__global__ __launch_bounds__(1024) void mm_kernel(
    const float* h, const float* __restrict__ t1, const float* __restrict__ t2,
    float* out, const float* __restrict__ W, const float* __restrict__ bias,
    const float* __restrict__ aP, float* __restrict__ bp, int N, int f_in_real) {
  __shared__ float W0m2[F_IN * F_OUT];
  __shared__ float W1s[F_IN * F_OUT];
  __shared__ float W2x2[F_IN * F_OUT];
  __shared__ float red[16 * 128];
  int tid = threadIdx.x;
  int stride = f_in_real * F_OUT;
  for (int idx = tid; idx < F_IN * F_OUT; idx += 1024) {
    int i = idx / F_OUT, col = idx - i * F_OUT;
    float w0 = 0.f, w1 = 0.f, w2 = 0.f;
    if (i < f_in_real) {
      int b = i * F_OUT + col;
      w0 = W[b]; w1 = W[stride + b]; w2 = W[2 * stride + b];
    }
    W0m2[idx] = w0 - w2;
    W1s[idx] = w1;
    W2x2[idx] = 2.f * w2;
  }
  __syncthreads();

  float alpha = aP[0];
  int lane = tid & 63, wid = tid >> 6;
  int gw = blockIdx.x * 16 + wid, nw = gridDim.x * 16;
  float ssum = 0.f, ssq = 0.f;

  for (int n = gw; n < N; n += nw) {
    float hr = 0.f, t1r = 0.f, t2r = 0.f;
    if (F_IN == 64 || lane < F_IN) {
      hr = h[n * F_IN + lane];
      t1r = t1[n * F_IN + lane];
      t2r = t2[n * F_IN + lane];
    }
    float acc = 0.f;
    if constexpr (F_OUT == 64) {
#pragma unroll
      for (int i = 0; i < F_IN; ++i) {
        float a = __shfl(hr, i), b2 = __shfl(t1r, i), c = __shfl(t2r, i);
        acc = fmaf(a, W0m2[i * F_OUT + lane], acc);
        acc = fmaf(b2, W1s[i * F_OUT + lane], acc);
        acc = fmaf(c, W2x2[i * F_OUT + lane], acc);
      }
      acc += bias[lane];
      acc = acc > 0.f ? acc : alpha * acc;
      out[n * F_OUT + lane] = acc;
      ssum += acc; ssq += acc * acc;
    } else {
      // F_OUT == 32: split i-range across wave halves, cols = lane&31
      int col = lane & 31, half = lane >> 5;
      int ibase = half * 32;
#pragma unroll
      for (int i = 0; i < 32; ++i) {
        int ie = i + ibase;
        float a = __shfl(hr, ie), b2 = __shfl(t1r, ie), c = __shfl(t2r, ie);
        acc = fmaf(a, W0m2[ie * 32 + col], acc);
        acc = fmaf(b2, W1s[ie * 32 + col], acc);
        acc = fmaf(c, W2x2[ie * 32 + col], acc);
      }
      acc += __shfl_xor(acc, 32);
      if (half == 0) {
        acc += bias[col];
        acc = acc > 0.f ? acc : alpha * acc;
        out[n * 64 + col] = acc;    // stride-64 rows, first 32 cols valid
        ssum += acc; ssq += acc * acc;
      }
    }
  }
  // block-level BN partial reduction (lanes beyond F_OUT hold 0)
  red[wid * 128 + lane] = ssum;
  red[wid * 128 + 64 + lane] = ssq;
  __syncthreads();
  if (tid < 128) {
    float s = 0.f;
#pragma unroll
    for (int w = 0; w < 16; ++w) s += red[w * 128 + tid];
    bp[blockIdx.x * 128 + tid] = s;
  }
}

// ---------------- BN stats reduce -> per-feature affine (s, t) ----------------

__global__ void stats_kernel(const float* __restrict__ bp, int nb,
                             const float* __restrict__ g, const float* __restrict__ be,
                             float* __restrict__ st, int F_OUT, float invN) {
  __shared__ float red[1024];
  int tid = threadIdx.x;
  int t = tid & 127, c = tid >> 7;
  float s = 0.f;
  for (int w = c; w < nb; w += 8) s += bp[w * 128 + t];
  red[tid] = s;
  __syncthreads();
  if (tid < 128) {
    float tot = 0.f;
    for (int cc = 0; cc < 8; ++cc) tot += red[cc * 128 + tid];
    red[tid] = tot;
  }
  __syncthreads();
  if (tid < F_OUT) {
    float sum = red[tid], sq = red[64 + tid];
    float mu = sum * invN;
    float var = sq * invN - mu * mu;
    float sc = g[tid] * rsqrtf(var + BN_EPS);
    st[tid] = sc;
    st[64 + tid] = be[tid] - mu * sc;
  }
}

// rows of rowF4 float4s; first activeF4 float4s of each row get the affine
__global__ void norm_kernel(float4* __restrict__ buf, const float* __restrict__ st,
                            int total, int shift, int rowF4) {
  int idx = blockIdx.x * blockDim.x + threadIdx.x;
  if (idx < total) {
    int n = idx >> shift, q = idx & ((1 << shift) - 1);
    float4 v = buf[n * rowF4 + q];
    int j = q * 4;
    v.x = v.x * st[j]     + st[64 + j];
    v.y = v.y * st[j + 1] + st[65 + j];
    v.z = v.z * st[j + 2] + st[66 + j];
    v.w = v.w * st[j + 3] + st[67 + j];
    buf[n * rowF4 + q] = v;
  }
}

// ---------------- final MLP: relu(h@w1+b1) -> relu(@w2+b2) -> @w3+b3 ----------------
// input rows have stride 64 floats, first 32 valid

__global__ __launch_bounds__(256) void mlp_kernel(const float* __restrict__ h,
    const float* __restrict__ w1, const float* __restrict__ b1,
    const float* __restrict__ w2, const float* __restrict__ b2,
    const float* __restrict__ w3, const float* __restrict__ b3,
    float* __restrict__ out, int N) {
  __shared__ float W1[1024], W2[1024], W3[1024], B1[32], B2[32], B3[32];
  int tid = threadIdx.x;
  for (int idx = tid; idx < 1024; idx += 256) {
    W1[idx] = w1[idx];
    W2[idx] = w2[idx];
    W3[idx] = w3[idx];
  }
  if (tid < 32) { B1[tid] = b1[tid]; B2[tid] = b2[tid]; B3[tid] = b3[tid]; }
  __syncthreads();
  int j = tid & 31;
  int n = blockIdx.x * 8 + (tid >> 5);
  if (n >= N) return;
  float v = h[n * 64 + j];
  float a1 = B1[j];
#pragma unroll
  for (int i = 0; i < 32; ++i) a1 += __shfl(v, i, 32) * W1[i * 32 + j];
  a1 = fmaxf(a1, 0.f);
  float a2 = B2[j];
#pragma unroll
  for (int i = 0; i < 32; ++i) a2 += __shfl(a1, i, 32) * W2[i * 32 + j];
  a2 = fmaxf(a2, 0.f);
  float a3 = B3[j];
#pragma unroll
  for (int i = 0; i < 32; ++i) a3 += __shfl(a2, i, 32) * W3[i * 32 + j];
  out[n * 32 + j] = a3;
}

// ---------------- host ----------------

extern "C" void kernel_launch(void* const* d_in, const int* in_sizes, int n_in,
                              void* d_out, int out_size, void* d_ws, size_t ws_size,
                              hipStream_t stream) {
  const float* x   = (const float*)d_in[0];
  const float* pos = (const float*)d_in[1];
  const float* nrm = (const float*)d_in[2];
  const int*   ei  = (const int*)d_in[3];
  const float* W1p = (const float*)d_in[4];
  const float* b1p = (const float*)d_in[5];
  const float* a1p = (const float*)d_in[6];
  const float* g1p = (const float*)d_in[7];
  const float* be1p= (const float*)d_in[8];
  const float* W2p = (const float*)d_in[9];
  const float* b2p = (const float*)d_in[10];
  const float* a2p = (const float*)d_in[11];
  const float* g2p = (const float*)d_in[12];
  const float* be2p= (const float*)d_in[13];
  const float* W3p = (const float*)d_in[14];
  const float* b3p = (const float*)d_in[15];
  const float* a3p = (const float*)d_in[16];
  const float* g3p = (const float*)d_in[17];
  const float* be3p= (const float*)d_in[18];
  const float* W4p = (const float*)d_in[19];
  const float* b4p = (const float*)d_in[20];
  const float* a4p = (const float*)d_in[21];
  const float* g4p = (const float*)d_in[22];
  const float* be4p= (const float*)d_in[23];
  const float* h1w = (const float*)d_in[24];
  const float* h1b = (const float*)d_in[25];
  const float* h2w = (const float*)d_in[26];
  const float* h2b = (const float*)d_in[27];
  const float* h3w = (const float*)d_in[28];
  const float* h3b = (const float*)d_in[29];

  const int N = in_sizes[0] / 3;
  const int E = in_sizes[3] / 2;
  const int* src = ei;
  const int* dst = ei + E;

  char* p = (char*)d_ws;
  auto alloc = [&](size_t bytes) -> void* {
    void* r = (void*)p;
    p += (bytes + 255) & ~(size_t)255;
    return r;
  };
  float* dis    = (float*)alloc((size_t)N * 4);
  int*   rowptr = (int*)  alloc((size_t)(N + 1) * 4);
  int*   cntA   = (int*)  alloc((size_t)N * 4);
  int*   cntB   = (int*)  alloc((size_t)N * 4);
  int*   bsums  = (int*)  alloc(4096 * 4);
  int*   srcS   = (int*)  alloc((size_t)E * 4);
  float* wS     = (float*)alloc((size_t)E * 4);
  float* bufH   = (float*)alloc((size_t)N * 64 * 4);
  float* bufT1  = (float*)alloc((size_t)N * 64 * 4);
  float* bufT2  = (float*)alloc((size_t)N * 64 * 4);
  float* bufH16 = (float*)alloc((size_t)N * 16 * 4);
  const int MMB = 512;                         // mm blocks (1024 thr, 2/CU)
  float* bp     = (float*)alloc((size_t)MMB * 128 * 4);
  float* stats  = (float*)alloc(256 * 4);

  hipMemsetAsync(cntA, 0, (size_t)N * 4, stream);
  hipMemsetAsync(cntB, 0, (size_t)N * 4, stream);
  int gE = (E + 255) / 256, gN = (N + 255) / 256;
  hist_kernel<<<gE, 256, 0, stream>>>(src, dst, E, cntA, cntB);
  dis_kernel<<<gN, 256, 0, stream>>>(cntA, dis, N);
  scan1_kernel<<<gN, 256, 0, stream>>>(cntB, N, rowptr, bsums);
  scan2_kernel<<<1, 1024, 0, stream>>>(bsums, gN, rowptr, N);
  scan3_kernel<<<gN, 256, 0, stream>>>(rowptr, bsums, N);
  hipMemsetAsync(cntB, 0, (size_t)N * 4, stream);
  scatter_kernel<<<gE, 256, 0, stream>>>(src, dst, E, rowptr, cntB, dis, srcS, wS);
  pack_kernel<<<(N * 16 + 255) / 256, 256, 0, stream>>>(x, pos, nrm, bufH16, N);

  const float invN = 1.f / (float)N;
  int g64 = (N + 3) / 4, g16 = (N + 15) / 16;
  int gNorm64 = (N * 16 + 255) / 256;   // N*16 float4s
  int gNorm32 = (N * 8 + 255) / 256;    // N*8 float4s

  // layer 1: 9(pad16) -> 64   h=bufH16, out=bufH
  lap16_kernel<<<g16, 256, 0, stream>>>((const float4*)bufH16, (float4*)bufT1, rowptr, srcS, wS, N);
  lap16_kernel<<<g16, 256, 0, stream>>>((const float4*)bufT1, (float4*)bufT2, rowptr, srcS, wS, N);
  mm_kernel<16, 64><<<MMB, 1024, 0, stream>>>(bufH16, bufT1, bufT2, bufH, W1p, b1p, a1p, bp, N, 9);
  stats_kernel<<<1, 1024, 0, stream>>>(bp, MMB, g1p, be1p, stats, 64, invN);
  norm_kernel<<<gNorm64, 256, 0, stream>>>((float4*)bufH, stats, N * 16, 4, 16);

  // layer 2: 64 -> 64 (in-place on bufH)
  lap64_kernel<<<g64, 256, 0, stream>>>((const float4*)bufH, (float4*)bufT1, rowptr, srcS, wS, N);
  lap64_kernel<<<g64, 256, 0, stream>>>((const float4*)bufT1, (float4*)bufT2, rowptr, srcS, wS, N);
  mm_kernel<64, 64><<<MMB, 1024, 0, stream>>>(bufH, bufT1, bufT2, bufH, W2p, b2p, a2p, bp, N, 64);
  stats_kernel<<<1, 1024, 0, stream>>>(bp, MMB, g2p, be2p, stats, 64, invN);
  norm_kernel<<<gNorm64, 256, 0, stream>>>((float4*)bufH, stats, N * 16, 4, 16);

  // layer 3: 64 -> 64 (in-place on bufH)
  lap64_kernel<<<g64, 256, 0, stream>>>((const float4*)bufH, (float4*)bufT1, rowptr, srcS, wS, N);
  lap64_kernel<<<g64, 256, 0, stream>>>((const float4*)bufT1, (float4*)bufT2, rowptr, srcS, wS, N);
  mm_kernel<64, 64><<<MMB, 1024, 0, stream>>>(bufH, bufT1, bufT2, bufH, W3p, b3p, a3p, bp, N, 64);
  stats_kernel<<<1, 1024, 0, stream>>>(bp, MMB, g3p, be3p, stats, 64, invN);
  norm_kernel<<<gNorm64, 256, 0, stream>>>((float4*)bufH, stats, N * 16, 4, 16);

  // layer 4: 64 -> 32 (out in bufH, stride-64 rows, first 32 cols)
  lap64_kernel<<<g64, 256, 0, stream>>>((const float4*)bufH, (float4*)bufT1, rowptr, srcS, wS, N);
  lap64_kernel<<<g64, 256, 0, stream>>>((const float4*)bufT1, (float4*)bufT2, rowptr, srcS, wS, N);
  mm_kernel<64, 32><<<MMB, 1024, 0, stream>>>(bufH, bufT1, bufT2, bufH, W4p, b4p, a4p, bp, N, 64);
  stats_kernel<<<1, 1024, 0, stream>>>(bp, MMB, g4p, be4p, stats, 32, invN);
  norm_kernel<<<gNorm32, 256, 0, stream>>>((float4*)bufH, stats, N * 8, 3, 16);

  // final MLP
  mlp_kernel<<<(N + 7) / 8, 256, 0, stream>>>(bufH, h1w, h1b, h2w, h2b, h3w, h3b, (float*)d_out, N);
}

// Round 3
// 2230.808 us; speedup vs baseline: 1.9426x; 1.0106x over previous
//
#include <hip/hip_runtime.h>

constexpr float BN_EPS = 1e-5f;

__device__ __forceinline__ float bcastf(float x, int l) {
  return __int_as_float(__builtin_amdgcn_readlane(__float_as_int(x), l));
}

// ---------------- graph preprocessing ----------------

__global__ void hist_kernel(const int* __restrict__ src, const int* __restrict__ dst, int E,
                            int* __restrict__ cntA, int* __restrict__ cntB) {
  int e = blockIdx.x * blockDim.x + threadIdx.x;
  if (e < E) {
    atomicAdd(&cntA[src[e]], 1);   // out-degree (deg in reference)
    atomicAdd(&cntB[dst[e]], 1);   // in-degree histogram for CSR by dst
  }
}

__global__ void dis_kernel(const int* __restrict__ cnt, float* __restrict__ dis, int N) {
  int n = blockIdx.x * blockDim.x + threadIdx.x;
  if (n < N) dis[n] = cnt[n] > 0 ? rsqrtf((float)cnt[n]) : 0.f;
}

__global__ void scan1_kernel(const int* __restrict__ cnt, int N,
                             int* __restrict__ rowptr, int* __restrict__ bsums) {
  int tid = threadIdx.x, lane = tid & 63, wid = tid >> 6;
  int i = blockIdx.x * 256 + tid;
  int v = (i < N) ? cnt[i] : 0;
  int incl = v;
#pragma unroll
  for (int off = 1; off < 64; off <<= 1) {
    int u = __shfl_up(incl, off);
    if (lane >= off) incl += u;
  }
  __shared__ int wt[4];
  if (lane == 63) wt[wid] = incl;
  __syncthreads();
  int woff = 0;
  for (int w = 0; w < wid; ++w) woff += wt[w];
  if (i < N) rowptr[i] = woff + incl - v;
  if (tid == 255) bsums[blockIdx.x] = woff + incl;
}

__global__ void scan2_kernel(int* __restrict__ bsums, int NB, int* __restrict__ rowptr, int N) {
  int tid = threadIdx.x, lane = tid & 63, wid = tid >> 6;
  int v = (tid < NB) ? bsums[tid] : 0;
  int incl = v;
#pragma unroll
  for (int off = 1; off < 64; off <<= 1) {
    int u = __shfl_up(incl, off);
    if (lane >= off) incl += u;
  }
  __shared__ int wt[16];
  if (lane == 63) wt[wid] = incl;
  __syncthreads();
  int woff = 0;
  for (int w = 0; w < wid; ++w) woff += wt[w];
  if (tid < NB) bsums[tid] = woff + incl - v;
  if (tid == blockDim.x - 1) rowptr[N] = woff + incl;
}

__global__ void scan3_kernel(int* __restrict__ rowptr, const int* __restrict__ bsums, int N) {
  int i = blockIdx.x * 256 + threadIdx.x;
  if (i < N) rowptr[i] += bsums[blockIdx.x];
}

__global__ void scatter_kernel(const int* __restrict__ src, const int* __restrict__ dst, int E,
                               const int* __restrict__ rowptr, int* __restrict__ cursor,
                               const float* __restrict__ dis,
                               int* __restrict__ srcS, float* __restrict__ wS) {
  int e = blockIdx.x * blockDim.x + threadIdx.x;
  if (e < E) {
    int s = src[e], d = dst[e];
    int p = rowptr[d] + atomicAdd(&cursor[d], 1);
    srcS[p] = s;
    wS[p] = -dis[s] * dis[d];
  }
}

__global__ void pack_kernel(const float* __restrict__ x, const float* __restrict__ pos,
                            const float* __restrict__ nrm, float* __restrict__ h0, int N) {
  int idx = blockIdx.x * blockDim.x + threadIdx.x;
  if (idx < N * 16) {
    int n = idx >> 4, c = idx & 15;
    float v = 0.f;
    if (c < 3) v = x[n * 3 + c];
    else if (c < 6) v = pos[n * 3 + c - 3];
    else if (c < 9) v = nrm[n * 3 + c - 6];
    h0[idx] = v;
  }
}

// ---------------- lap (vectorized): out = L_hat @ v ----------------
// F=64: one node per wave; lanes = 4 edge-slots x 16 float4

__global__ __launch_bounds__(256) void lap64_kernel(const float4* __restrict__ v, float4* __restrict__ out,
                                                    const int* __restrict__ rowptr,
                                                    const int* __restrict__ srcS,
                                                    const float* __restrict__ wS, int N) {
  int tid = threadIdx.x, lane = tid & 63, wid = tid >> 6;
  int node = blockIdx.x * 4 + wid;
  if (node >= N) return;
  int g = lane >> 4, q = lane & 15;
  int r0 = rowptr[node], r1 = rowptr[node + 1];
  float4 acc = {0.f, 0.f, 0.f, 0.f}, acc2 = {0.f, 0.f, 0.f, 0.f};
  int k = r0 + g;
  for (; k + 4 < r1; k += 8) {
    int s0 = srcS[k];     float w0 = wS[k];     float4 t0 = v[s0 * 16 + q];
    int s1 = srcS[k + 4]; float w1 = wS[k + 4]; float4 t1 = v[s1 * 16 + q];
    acc.x  += w0 * t0.x; acc.y  += w0 * t0.y; acc.z  += w0 * t0.z; acc.w  += w0 * t0.w;
    acc2.x += w1 * t1.x; acc2.y += w1 * t1.y; acc2.z += w1 * t1.z; acc2.w += w1 * t1.w;
  }
  if (k < r1) {
    int s = srcS[k]; float w = wS[k]; float4 t = v[s * 16 + q];
    acc.x += w * t.x; acc.y += w * t.y; acc.z += w * t.z; acc.w += w * t.w;
  }
  acc.x += acc2.x; acc.y += acc2.y; acc.z += acc2.z; acc.w += acc2.w;
  acc.x += __shfl_xor(acc.x, 16); acc.y += __shfl_xor(acc.y, 16);
  acc.z += __shfl_xor(acc.z, 16); acc.w += __shfl_xor(acc.w, 16);
  acc.x += __shfl_xor(acc.x, 32); acc.y += __shfl_xor(acc.y, 32);
  acc.z += __shfl_xor(acc.z, 32); acc.w += __shfl_xor(acc.w, 32);
  if (g == 0) out[node * 16 + q] = acc;
}

// F=16: 4 nodes per wave; per node 16 lanes = 4 edge-slots x 4 float4

__global__ __launch_bounds__(256) void lap16_kernel(const float4* __restrict__ v, float4* __restrict__ out,
                                                    const int* __restrict__ rowptr,
                                                    const int* __restrict__ srcS,
                                                    const float* __restrict__ wS, int N) {
  int tid = threadIdx.x, lane = tid & 63, wid = tid >> 6;
  int node = (blockIdx.x * 4 + wid) * 4 + (lane >> 4);
  int sub = lane & 15, g = sub >> 2, q = sub & 3;
  float4 acc = {0.f, 0.f, 0.f, 0.f};
  if (node < N) {
    int r0 = rowptr[node], r1 = rowptr[node + 1];
    for (int k = r0 + g; k < r1; k += 4) {
      int s = srcS[k]; float w = wS[k]; float4 t = v[s * 4 + q];
      acc.x += w * t.x; acc.y += w * t.y; acc.z += w * t.z; acc.w += w * t.w;
    }
  }
  acc.x += __shfl_xor(acc.x, 4); acc.y += __shfl_xor(acc.y, 4);
  acc.z += __shfl_xor(acc.z, 4); acc.w += __shfl_xor(acc.w, 4);
  acc.x += __shfl_xor(acc.x, 8); acc.y += __shfl_xor(acc.y, 8);
  acc.z += __shfl_xor(acc.z, 8); acc.w += __shfl_xor(acc.w, 8);
  if (node < N && g == 0) out[node * 4 + q] = acc;
}

// ---------------- streaming matmul: out = h@(W0-W2)+t1@W1+t2@(2W2)+b; PReLU; BN partials ----------------
// 1 node per wave, lane = output col; input-row broadcast via v_readlane (VALU pipe),
// only the W reads touch LDS (b32, conflict-free). out may alias h/t1/t2 per-row
// (row n is read before written, and only by its owning wave) -> NO __restrict__.

template <int F_IN, int F_OUT>
__global__ __launch_bounds__(1024) void mm_kernel(
    const float* h, const float* t1, const float* t2,
    float* out, const float* W, const float* bias,
    const float* aP, float* __restrict__ bp, int N, int f_in_real) {
  __shared__ float W0m2[F_IN * F_OUT];
  __shared__ float W1s[F_IN * F_OUT];
  __shared__ float W2x2[F_IN * F_OUT];
  __shared__ float red[16 * 128];
  int tid = threadIdx.x;
  int stride = f_in_real * F_OUT;
  for (int idx = tid; idx < F_IN * F_OUT; idx += 1024) {
    int i = idx / F_OUT, col = idx - i * F_OUT;
    float w0 = 0.f, w1 = 0.f, w2 = 0.f;
    if (i < f_in_real) {
      int b = i * F_OUT + col;
      w0 = W[b]; w1 = W[stride + b]; w2 = W[2 * stride + b];
    }
    W0m2[idx] = w0 - w2;
    W1s[idx] = w1;
    W2x2[idx] = 2.f * w2;
  }
  __syncthreads();

  float alpha = aP[0];
  int lane = tid & 63, wid = tid >> 6;
  int gw = blockIdx.x * 16 + wid, nw = gridDim.x * 16;
  int col = lane & (F_OUT - 1);
  bool active = (F_OUT == 64) || (lane < F_OUT);
  float ssum = 0.f, ssq = 0.f;

  for (int n = gw; n < N; n += nw) {
    float hr = 0.f, t1r = 0.f, t2r = 0.f;
    if (F_IN == 64 || lane < F_IN) {
      hr  = h [(size_t)n * F_IN + lane];
      t1r = t1[(size_t)n * F_IN + lane];
      t2r = t2[(size_t)n * F_IN + lane];
    }
    float a0 = 0.f, a1 = 0.f, a2 = 0.f;
#pragma unroll
    for (int i = 0; i < F_IN; ++i) {
      float a = bcastf(hr, i), b = bcastf(t1r, i), c = bcastf(t2r, i);
      a0 = fmaf(a, W0m2[i * F_OUT + col], a0);
      a1 = fmaf(b, W1s [i * F_OUT + col], a1);
      a2 = fmaf(c, W2x2[i * F_OUT + col], a2);
    }
    float acc = a0 + a1 + a2 + bias[col];
    acc = acc > 0.f ? acc : alpha * acc;   // PReLU
    if (active) {
      out[(size_t)n * 64 + col] = acc;     // row stride always 64 floats
      ssum += acc; ssq += acc * acc;
    }
  }
  // block-level BN partial reduction (inactive lanes hold 0)
  red[wid * 128 + lane] = (active && lane < 64) ? ssum : 0.f;
  red[wid * 128 + 64 + lane] = (active && lane < 64) ? ssq : 0.f;
  __syncthreads();
  if (tid < 128) {
    float s = 0.f;
#pragma unroll
    for (int w = 0; w < 16; ++w) s += red[w * 128 + tid];
    bp[blockIdx.x * 128 + tid] = s;
  }
}

// ---------------- BN stats reduce -> per-feature affine (s, t) ----------------

__global__ void stats_kernel(const float* __restrict__ bp, int nb,
                             const float* __restrict__ g, const float* __restrict__ be,
                             float* __restrict__ st, int F_OUT, float invN) {
  __shared__ float red[1024];
  int tid = threadIdx.x;
  int t = tid & 127, c = tid >> 7;
  float s = 0.f;
  for (int w = c; w < nb; w += 8) s += bp[w * 128 + t];
  red[tid] = s;
  __syncthreads();
  if (tid < 128) {
    float tot = 0.f;
    for (int cc = 0; cc < 8; ++cc) tot += red[cc * 128 + tid];
    red[tid] = tot;
  }
  __syncthreads();
  if (tid < F_OUT) {
    float sum = red[tid], sq = red[64 + tid];
    float mu = sum * invN;
    float var = sq * invN - mu * mu;
    float sc = g[tid] * rsqrtf(var + BN_EPS);
    st[tid] = sc;
    st[64 + tid] = be[tid] - mu * sc;
  }
}

// rows of rowF4 float4s; first (1<<shift) float4s of each row get the affine
__global__ void norm_kernel(float4* __restrict__ buf, const float* __restrict__ st,
                            int total, int shift, int rowF4) {
  int idx = blockIdx.x * blockDim.x + threadIdx.x;
  if (idx < total) {
    int n = idx >> shift, q = idx & ((1 << shift) - 1);
    float4 v = buf[n * rowF4 + q];
    int j = q * 4;
    v.x = v.x * st[j]     + st[64 + j];
    v.y = v.y * st[j + 1] + st[65 + j];
    v.z = v.z * st[j + 2] + st[66 + j];
    v.w = v.w * st[j + 3] + st[67 + j];
    buf[n * rowF4 + q] = v;
  }
}

// ---------------- final MLP: relu(h@w1+b1) -> relu(@w2+b2) -> @w3+b3 ----------------
// input rows have stride 64 floats, first 32 valid

__global__ __launch_bounds__(256) void mlp_kernel(const float* __restrict__ h,
    const float* __restrict__ w1, const float* __restrict__ b1,
    const float* __restrict__ w2, const float* __restrict__ b2,
    const float* __restrict__ w3, const float* __restrict__ b3,
    float* __restrict__ out, int N) {
  __shared__ float W1[1024], W2[1024], W3[1024], B1[32], B2[32], B3[32];
  int tid = threadIdx.x;
  for (int idx = tid; idx < 1024; idx += 256) {
    W1[idx] = w1[idx];
    W2[idx] = w2[idx];
    W3[idx] = w3[idx];
  }
  if (tid < 32) { B1[tid] = b1[tid]; B2[tid] = b2[tid]; B3[tid] = b3[tid]; }
  __syncthreads();
  int j = tid & 31;
  int n = blockIdx.x * 8 + (tid >> 5);
  if (n >= N) return;
  float v = h[n * 64 + j];
  float a1 = B1[j];
#pragma unroll
  for (int i = 0; i < 32; ++i) a1 += __shfl(v, i, 32) * W1[i * 32 + j];
  a1 = fmaxf(a1, 0.f);
  float a2 = B2[j];
#pragma unroll
  for (int i = 0; i < 32; ++i) a2 += __shfl(a1, i, 32) * W2[i * 32 + j];
  a2 = fmaxf(a2, 0.f);
  float a3 = B3[j];
#pragma unroll
  for (int i = 0; i < 32; ++i) a3 += __shfl(a2, i, 32) * W3[i * 32 + j];
  out[n * 32 + j] = a3;
}

// ---------------- host ----------------

extern "C" void kernel_launch(void* const* d_in, const int* in_sizes, int n_in,
                              void* d_out, int out_size, void* d_ws, size_t ws_size,
                              hipStream_t stream) {
  const float* x   = (const float*)d_in[0];
  const float* pos = (const float*)d_in[1];
  const float* nrm = (const float*)d_in[2];
  const int*   ei  = (const int*)d_in[3];
  const float* W1p = (const float*)d_in[4];
  const float* b1p = (const float*)d_in[5];
  const float* a1p = (const float*)d_in[6];
  const float* g1p = (const float*)d_in[7];
  const float* be1p= (const float*)d_in[8];
  const float* W2p = (const float*)d_in[9];
  const float* b2p = (const float*)d_in[10];
  const float* a2p = (const float*)d_in[11];
  const float* g2p = (const float*)d_in[12];
  const float* be2p= (const float*)d_in[13];
  const float* W3p = (const float*)d_in[14];
  const float* b3p = (const float*)d_in[15];
  const float* a3p = (const float*)d_in[16];
  const float* g3p = (const float*)d_in[17];
  const float* be3p= (const float*)d_in[18];
  const float* W4p = (const float*)d_in[19];
  const float* b4p = (const float*)d_in[20];
  const float* a4p = (const float*)d_in[21];
  const float* g4p = (const float*)d_in[22];
  const float* be4p= (const float*)d_in[23];
  const float* h1w = (const float*)d_in[24];
  const float* h1b = (const float*)d_in[25];
  const float* h2w = (const float*)d_in[26];
  const float* h2b = (const float*)d_in[27];
  const float* h3w = (const float*)d_in[28];
  const float* h3b = (const float*)d_in[29];

  const int N = in_sizes[0] / 3;
  const int E = in_sizes[3] / 2;
  const int* src = ei;
  const int* dst = ei + E;

  char* p = (char*)d_ws;
  auto alloc = [&](size_t bytes) -> void* {
    void* r = (void*)p;
    p += (bytes + 255) & ~(size_t)255;
    return r;
  };
  float* dis    = (float*)alloc((size_t)N * 4);
  int*   rowptr = (int*)  alloc((size_t)(N + 1) * 4);
  int*   cntA   = (int*)  alloc((size_t)N * 4);
  int*   cntB   = (int*)  alloc((size_t)N * 4);
  int*   bsums  = (int*)  alloc(4096 * 4);
  int*   srcS   = (int*)  alloc((size_t)E * 4);
  float* wS     = (float*)alloc((size_t)E * 4);
  float* bufH   = (float*)alloc((size_t)N * 64 * 4);
  float* bufT1  = (float*)alloc((size_t)N * 64 * 4);
  float* bufT2  = (float*)alloc((size_t)N * 64 * 4);
  float* bufH16 = (float*)alloc((size_t)N * 16 * 4);
  const int MMB = 512;                         // mm blocks (1024 thr, 2/CU)
  float* bp     = (float*)alloc((size_t)MMB * 128 * 4);
  float* stats  = (float*)alloc(256 * 4);

  hipMemsetAsync(cntA, 0, (size_t)N * 4, stream);
  hipMemsetAsync(cntB, 0, (size_t)N * 4, stream);
  int gE = (E + 255) / 256, gN = (N + 255) / 256;
  hist_kernel<<<gE, 256, 0, stream>>>(src, dst, E, cntA, cntB);
  dis_kernel<<<gN, 256, 0, stream>>>(cntA, dis, N);
  scan1_kernel<<<gN, 256, 0, stream>>>(cntB, N, rowptr, bsums);
  scan2_kernel<<<1, 1024, 0, stream>>>(bsums, gN, rowptr, N);
  scan3_kernel<<<gN, 256, 0, stream>>>(rowptr, bsums, N);
  hipMemsetAsync(cntB, 0, (size_t)N * 4, stream);
  scatter_kernel<<<gE, 256, 0, stream>>>(src, dst, E, rowptr, cntB, dis, srcS, wS);
  pack_kernel<<<(N * 16 + 255) / 256, 256, 0, stream>>>(x, pos, nrm, bufH16, N);

  const float invN = 1.f / (float)N;
  int g64 = (N + 3) / 4, g16 = (N + 15) / 16;
  int gNorm64 = (N * 16 + 255) / 256;   // N*16 float4s
  int gNorm32 = (N * 8 + 255) / 256;    // N*8 float4s

  // layer 1: 9(pad16) -> 64   h=bufH16, out=bufH
  lap16_kernel<<<g16, 256, 0, stream>>>((const float4*)bufH16, (float4*)bufT1, rowptr, srcS, wS, N);
  lap16_kernel<<<g16, 256, 0, stream>>>((const float4*)bufT1, (float4*)bufT2, rowptr, srcS, wS, N);
  mm_kernel<16, 64><<<MMB, 1024, 0, stream>>>(bufH16, bufT1, bufT2, bufH, W1p, b1p, a1p, bp, N, 9);
  stats_kernel<<<1, 1024, 0, stream>>>(bp, MMB, g1p, be1p, stats, 64, invN);
  norm_kernel<<<gNorm64, 256, 0, stream>>>((float4*)bufH, stats, N * 16, 4, 16);

  // layer 2: 64 -> 64 (in-place on bufH)
  lap64_kernel<<<g64, 256, 0, stream>>>((const float4*)bufH, (float4*)bufT1, rowptr, srcS, wS, N);
  lap64_kernel<<<g64, 256, 0, stream>>>((const float4*)bufT1, (float4*)bufT2, rowptr, srcS, wS, N);
  mm_kernel<64, 64><<<MMB, 1024, 0, stream>>>(bufH, bufT1, bufT2, bufH, W2p, b2p, a2p, bp, N, 64);
  stats_kernel<<<1, 1024, 0, stream>>>(bp, MMB, g2p, be2p, stats, 64, invN);
  norm_kernel<<<gNorm64, 256, 0, stream>>>((float4*)bufH, stats, N * 16, 4, 16);

  // layer 3: 64 -> 64 (in-place on bufH)
  lap64_kernel<<<g64, 256, 0, stream>>>((const float4*)bufH, (float4*)bufT1, rowptr, srcS, wS, N);
  lap64_kernel<<<g64, 256, 0, stream>>>((const float4*)bufT1, (float4*)bufT2, rowptr, srcS, wS, N);
  mm_kernel<64, 64><<<MMB, 1024, 0, stream>>>(bufH, bufT1, bufT2, bufH, W3p, b3p, a3p, bp, N, 64);
  stats_kernel<<<1, 1024, 0, stream>>>(bp, MMB, g3p, be3p, stats, 64, invN);
  norm_kernel<<<gNorm64, 256, 0, stream>>>((float4*)bufH, stats, N * 16, 4, 16);

  // layer 4: 64 -> 32 (out in bufH, stride-64 rows, first 32 cols)
  lap64_kernel<<<g64, 256, 0, stream>>>((const float4*)bufH, (float4*)bufT1, rowptr, srcS, wS, N);
  lap64_kernel<<<g64, 256, 0, stream>>>((const float4*)bufT1, (float4*)bufT2, rowptr, srcS, wS, N);
  mm_kernel<64, 32><<<MMB, 1024, 0, stream>>>(bufH, bufT1, bufT2, bufH, W4p, b4p, a4p, bp, N, 64);
  stats_kernel<<<1, 1024, 0, stream>>>(bp, MMB, g4p, be4p, stats, 32, invN);
  norm_kernel<<<gNorm32, 256, 0, stream>>>((float4*)bufH, stats, N * 8, 3, 16);

  // final MLP
  mlp_kernel<<<(N + 7) / 8, 256, 0, stream>>>(bufH, h1w, h1b, h2w, h2b, h3w, h3b, (float*)d_out, N);
}

// Round 4
// 1521.635 us; speedup vs baseline: 2.8480x; 1.4661x over previous
//
#include <hip/hip_runtime.h>

constexpr float BN_EPS = 1e-5f;

// ---------------- graph preprocessing ----------------

__global__ void hist_kernel(const int* __restrict__ src, const int* __restrict__ dst, int E,
                            int* __restrict__ cntA, int* __restrict__ cntB) {
  int e = blockIdx.x * blockDim.x + threadIdx.x;
  if (e < E) {
    atomicAdd(&cntA[src[e]], 1);   // out-degree (deg in reference)
    atomicAdd(&cntB[dst[e]], 1);   // in-degree histogram for CSR by dst
  }
}

__global__ void dis_kernel(const int* __restrict__ cnt, float* __restrict__ dis, int N) {
  int n = blockIdx.x * blockDim.x + threadIdx.x;
  if (n < N) dis[n] = cnt[n] > 0 ? rsqrtf((float)cnt[n]) : 0.f;
}

__global__ void scan1_kernel(const int* __restrict__ cnt, int N,
                             int* __restrict__ rowptr, int* __restrict__ bsums) {
  int tid = threadIdx.x, lane = tid & 63, wid = tid >> 6;
  int i = blockIdx.x * 256 + tid;
  int v = (i < N) ? cnt[i] : 0;
  int incl = v;
#pragma unroll
  for (int off = 1; off < 64; off <<= 1) {
    int u = __shfl_up(incl, off);
    if (lane >= off) incl += u;
  }
  __shared__ int wt[4];
  if (lane == 63) wt[wid] = incl;
  __syncthreads();
  int woff = 0;
  for (int w = 0; w < wid; ++w) woff += wt[w];
  if (i < N) rowptr[i] = woff + incl - v;
  if (tid == 255) bsums[blockIdx.x] = woff + incl;
}

__global__ void scan2_kernel(int* __restrict__ bsums, int NB, int* __restrict__ rowptr, int N) {
  int tid = threadIdx.x, lane = tid & 63, wid = tid >> 6;
  int v = (tid < NB) ? bsums[tid] : 0;
  int incl = v;
#pragma unroll
  for (int off = 1; off < 64; off <<= 1) {
    int u = __shfl_up(incl, off);
    if (lane >= off) incl += u;
  }
  __shared__ int wt[16];
  if (lane == 63) wt[wid] = incl;
  __syncthreads();
  int woff = 0;
  for (int w = 0; w < wid; ++w) woff += wt[w];
  if (tid < NB) bsums[tid] = woff + incl - v;
  if (tid == blockDim.x - 1) rowptr[N] = woff + incl;
}

__global__ void scan3_kernel(int* __restrict__ rowptr, const int* __restrict__ bsums, int N) {
  int i = blockIdx.x * 256 + threadIdx.x;
  if (i < N) rowptr[i] += bsums[blockIdx.x];
}

__global__ void scatter_kernel(const int* __restrict__ src, const int* __restrict__ dst, int E,
                               const int* __restrict__ rowptr, int* __restrict__ cursor,
                               const float* __restrict__ dis,
                               int* __restrict__ srcS, float* __restrict__ wS) {
  int e = blockIdx.x * blockDim.x + threadIdx.x;
  if (e < E) {
    int s = src[e], d = dst[e];
    int p = rowptr[d] + atomicAdd(&cursor[d], 1);
    srcS[p] = s;
    wS[p] = -dis[s] * dis[d];
  }
}

__global__ void pack_kernel(const float* __restrict__ x, const float* __restrict__ pos,
                            const float* __restrict__ nrm, float* __restrict__ h0, int N) {
  int idx = blockIdx.x * blockDim.x + threadIdx.x;
  if (idx < N * 16) {
    int n = idx >> 4, c = idx & 15;
    float v = 0.f;
    if (c < 3) v = x[n * 3 + c];
    else if (c < 6) v = pos[n * 3 + c - 3];
    else if (c < 9) v = nrm[n * 3 + c - 6];
    h0[idx] = v;
  }
}

// ---------------- lap (vectorized): out = L_hat @ v ----------------

__global__ __launch_bounds__(256) void lap64_kernel(const float4* __restrict__ v, float4* __restrict__ out,
                                                    const int* __restrict__ rowptr,
                                                    const int* __restrict__ srcS,
                                                    const float* __restrict__ wS, int N) {
  int tid = threadIdx.x, lane = tid & 63, wid = tid >> 6;
  int node = blockIdx.x * 4 + wid;
  if (node >= N) return;
  int g = lane >> 4, q = lane & 15;
  int r0 = rowptr[node], r1 = rowptr[node + 1];
  float4 acc = {0.f, 0.f, 0.f, 0.f}, acc2 = {0.f, 0.f, 0.f, 0.f};
  int k = r0 + g;
  for (; k + 4 < r1; k += 8) {
    int s0 = srcS[k];     float w0 = wS[k];     float4 t0 = v[s0 * 16 + q];
    int s1 = srcS[k + 4]; float w1 = wS[k + 4]; float4 t1 = v[s1 * 16 + q];
    acc.x  += w0 * t0.x; acc.y  += w0 * t0.y; acc.z  += w0 * t0.z; acc.w  += w0 * t0.w;
    acc2.x += w1 * t1.x; acc2.y += w1 * t1.y; acc2.z += w1 * t1.z; acc2.w += w1 * t1.w;
  }
  if (k < r1) {
    int s = srcS[k]; float w = wS[k]; float4 t = v[s * 16 + q];
    acc.x += w * t.x; acc.y += w * t.y; acc.z += w * t.z; acc.w += w * t.w;
  }
  acc.x += acc2.x; acc.y += acc2.y; acc.z += acc2.z; acc.w += acc2.w;
  acc.x += __shfl_xor(acc.x, 16); acc.y += __shfl_xor(acc.y, 16);
  acc.z += __shfl_xor(acc.z, 16); acc.w += __shfl_xor(acc.w, 16);
  acc.x += __shfl_xor(acc.x, 32); acc.y += __shfl_xor(acc.y, 32);
  acc.z += __shfl_xor(acc.z, 32); acc.w += __shfl_xor(acc.w, 32);
  if (g == 0) out[node * 16 + q] = acc;
}

__global__ __launch_bounds__(256) void lap16_kernel(const float4* __restrict__ v, float4* __restrict__ out,
                                                    const int* __restrict__ rowptr,
                                                    const int* __restrict__ srcS,
                                                    const float* __restrict__ wS, int N) {
  int tid = threadIdx.x, lane = tid & 63, wid = tid >> 6;
  int node = (blockIdx.x * 4 + wid) * 4 + (lane >> 4);
  int sub = lane & 15, g = sub >> 2, q = sub & 3;
  float4 acc = {0.f, 0.f, 0.f, 0.f};
  if (node < N) {
    int r0 = rowptr[node], r1 = rowptr[node + 1];
    for (int k = r0 + g; k < r1; k += 4) {
      int s = srcS[k]; float w = wS[k]; float4 t = v[s * 4 + q];
      acc.x += w * t.x; acc.y += w * t.y; acc.z += w * t.z; acc.w += w * t.w;
    }
  }
  acc.x += __shfl_xor(acc.x, 4); acc.y += __shfl_xor(acc.y, 4);
  acc.z += __shfl_xor(acc.z, 4); acc.w += __shfl_xor(acc.w, 4);
  acc.x += __shfl_xor(acc.x, 8); acc.y += __shfl_xor(acc.y, 8);
  acc.z += __shfl_xor(acc.z, 8); acc.w += __shfl_xor(acc.w, 8);
  if (node < N && g == 0) out[node * 4 + q] = acc;
}

// ---------------- register-tiled GEMM mm ----------------
// C[N x F_OUT] = [h|t1|t2] @ [W0-W2; W1; 2*W2] + b, PReLU, BN partials.
// Block: 256 threads, tile = 128 nodes. Per-thread micro-tile: 4 nodes x CPT cols.
// B staged in LDS once (reused across grid-stride tiles); A read direct from
// global (8 distinct rows/wave-instr, L1 broadcast). Out rows stride 64.
// In-place safe: a block reads only its own tile's rows, writes them after.

template <int F_IN, int F_OUT>
__global__ __launch_bounds__(256) void mm_kernel(
    const float* h, const float* t1, const float* t2,
    float* out, const float* __restrict__ W, const float* __restrict__ bias,
    const float* __restrict__ aP, float* __restrict__ bp, int N, int f_in_real, int ntiles) {
  constexpr int CPT = (F_OUT == 64) ? 8 : 4;       // cols per thread
  constexpr int WSZ = 3 * F_IN * F_OUT;            // staged W floats
  constexpr int RSZ = 32 * F_OUT * 2;              // reduction floats
  constexpr int SM = (WSZ > RSZ) ? WSZ : RSZ;
  __shared__ float sm[SM];

  int tid = threadIdx.x;
  const int S = f_in_real * F_OUT;
  for (int idx = tid; idx < WSZ; idx += 256) {
    int m = idx / (F_IN * F_OUT);
    int r = idx - m * (F_IN * F_OUT);
    int i = r / F_OUT, c = r - i * F_OUT;
    float v = 0.f;
    if (i < f_in_real) {
      int b = i * F_OUT + c;
      if (m == 0)      v = W[b] - W[2 * S + b];
      else if (m == 1) v = W[S + b];
      else             v = 2.f * W[2 * S + b];
    }
    sm[idx] = v;
  }
  __syncthreads();

  const int cg = tid & 7;          // 8 col groups
  const int ngt = tid >> 3;        // 32 node groups x 4 nodes = 128
  const int c0 = cg * CPT;
  const float alpha = aP[0];
  float bb[CPT];
#pragma unroll
  for (int c = 0; c < CPT; ++c) bb[c] = bias[c0 + c];

  float ssum[CPT], ssq[CPT];
#pragma unroll
  for (int c = 0; c < CPT; ++c) { ssum[c] = 0.f; ssq[c] = 0.f; }

  for (int tile = blockIdx.x; tile < ntiles; tile += gridDim.x) {
    const int node0 = tile * 128 + ngt * 4;
    float acc[4][CPT];
#pragma unroll
    for (int j = 0; j < 4; ++j)
#pragma unroll
      for (int c = 0; c < CPT; ++c) acc[j][c] = 0.f;

    const float* As[3] = {h + (size_t)node0 * F_IN, t1 + (size_t)node0 * F_IN, t2 + (size_t)node0 * F_IN};
#pragma unroll
    for (int m = 0; m < 3; ++m) {
      const float* A = As[m];
      const float* Bm = sm + m * F_IN * F_OUT;
#pragma unroll 2
      for (int kb = 0; kb < F_IN / 4; ++kb) {
        float ar[4][4];
#pragma unroll
        for (int j = 0; j < 4; ++j)
          *(float4*)ar[j] = *(const float4*)(A + j * F_IN + kb * 4);
#pragma unroll
        for (int kk = 0; kk < 4; ++kk) {
          const float* Brow = Bm + (kb * 4 + kk) * F_OUT + c0;
          float br[CPT];
          *(float4*)br = *(const float4*)Brow;
          if (CPT == 8) *(float4*)(br + 4) = *(const float4*)(Brow + 4);
#pragma unroll
          for (int j = 0; j < 4; ++j)
#pragma unroll
            for (int c = 0; c < CPT; ++c)
              acc[j][c] = fmaf(ar[j][kk], br[c], acc[j][c]);
        }
      }
    }

    // epilogue: bias, PReLU, store (row stride 64), BN partial accumulation
#pragma unroll
    for (int j = 0; j < 4; ++j) {
      int node = node0 + j;
      if (node < N) {
        float v[CPT];
#pragma unroll
        for (int c = 0; c < CPT; ++c) {
          float t = acc[j][c] + bb[c];
          t = t > 0.f ? t : alpha * t;
          v[c] = t;
          ssum[c] += t;
          ssq[c] += t * t;
        }
        float* o = out + (size_t)node * 64 + c0;
        *(float4*)o = *(float4*)v;
        if (CPT == 8) *(float4*)(o + 4) = *(float4*)(v + 4);
      }
    }
  }

  // block reduction of BN partials (reuse sm after barrier)
  __syncthreads();
#pragma unroll
  for (int c = 0; c < CPT; ++c) {
    sm[(ngt * F_OUT + c0 + c) * 2 + 0] = ssum[c];
    sm[(ngt * F_OUT + c0 + c) * 2 + 1] = ssq[c];
  }
  __syncthreads();
  if (tid < 128) {
    int col = tid & 63, stat = tid >> 6;
    float tot = 0.f;
    if (col < F_OUT) {
#pragma unroll 8
      for (int g = 0; g < 32; ++g) tot += sm[(g * F_OUT + col) * 2 + stat];
    }
    bp[(size_t)blockIdx.x * 128 + stat * 64 + col] = tot;
  }
}

// ---------------- BN stats reduce -> per-feature affine (s, t) ----------------

__global__ void stats_kernel(const float* __restrict__ bp, int nb,
                             const float* __restrict__ g, const float* __restrict__ be,
                             float* __restrict__ st, int F_OUT, float invN) {
  __shared__ float red[1024];
  int tid = threadIdx.x;
  int t = tid & 127, c = tid >> 7;
  float s = 0.f;
  for (int w = c; w < nb; w += 8) s += bp[(size_t)w * 128 + t];
  red[tid] = s;
  __syncthreads();
  if (tid < 128) {
    float tot = 0.f;
    for (int cc = 0; cc < 8; ++cc) tot += red[cc * 128 + tid];
    red[tid] = tot;
  }
  __syncthreads();
  if (tid < F_OUT) {
    float sum = red[tid], sq = red[64 + tid];
    float mu = sum * invN;
    float var = sq * invN - mu * mu;
    float sc = g[tid] * rsqrtf(var + BN_EPS);
    st[tid] = sc;
    st[64 + tid] = be[tid] - mu * sc;
  }
}

__global__ void norm_kernel(float4* __restrict__ buf, const float* __restrict__ st,
                            int total, int shift, int rowF4) {
  int idx = blockIdx.x * blockDim.x + threadIdx.x;
  if (idx < total) {
    int n = idx >> shift, q = idx & ((1 << shift) - 1);
    float4 v = buf[n * rowF4 + q];
    int j = q * 4;
    v.x = v.x * st[j]     + st[64 + j];
    v.y = v.y * st[j + 1] + st[65 + j];
    v.z = v.z * st[j + 2] + st[66 + j];
    v.w = v.w * st[j + 3] + st[67 + j];
    buf[n * rowF4 + q] = v;
  }
}

// ---------------- final MLP ----------------

__global__ __launch_bounds__(256) void mlp_kernel(const float* __restrict__ h,
    const float* __restrict__ w1, const float* __restrict__ b1,
    const float* __restrict__ w2, const float* __restrict__ b2,
    const float* __restrict__ w3, const float* __restrict__ b3,
    float* __restrict__ out, int N) {
  __shared__ float W1[1024], W2[1024], W3[1024], B1[32], B2[32], B3[32];
  int tid = threadIdx.x;
  for (int idx = tid; idx < 1024; idx += 256) {
    W1[idx] = w1[idx];
    W2[idx] = w2[idx];
    W3[idx] = w3[idx];
  }
  if (tid < 32) { B1[tid] = b1[tid]; B2[tid] = b2[tid]; B3[tid] = b3[tid]; }
  __syncthreads();
  int j = tid & 31;
  int n = blockIdx.x * 8 + (tid >> 5);
  if (n >= N) return;
  float v = h[n * 64 + j];
  float a1 = B1[j];
#pragma unroll
  for (int i = 0; i < 32; ++i) a1 += __shfl(v, i, 32) * W1[i * 32 + j];
  a1 = fmaxf(a1, 0.f);
  float a2 = B2[j];
#pragma unroll
  for (int i = 0; i < 32; ++i) a2 += __shfl(a1, i, 32) * W2[i * 32 + j];
  a2 = fmaxf(a2, 0.f);
  float a3 = B3[j];
#pragma unroll
  for (int i = 0; i < 32; ++i) a3 += __shfl(a2, i, 32) * W3[i * 32 + j];
  out[n * 32 + j] = a3;
}

// ---------------- host ----------------

extern "C" void kernel_launch(void* const* d_in, const int* in_sizes, int n_in,
                              void* d_out, int out_size, void* d_ws, size_t ws_size,
                              hipStream_t stream) {
  const float* x   = (const float*)d_in[0];
  const float* pos = (const float*)d_in[1];
  const float* nrm = (const float*)d_in[2];
  const int*   ei  = (const int*)d_in[3];
  const float* W1p = (const float*)d_in[4];
  const float* b1p = (const float*)d_in[5];
  const float* a1p = (const float*)d_in[6];
  const float* g1p = (const float*)d_in[7];
  const float* be1p= (const float*)d_in[8];
  const float* W2p = (const float*)d_in[9];
  const float* b2p = (const float*)d_in[10];
  const float* a2p = (const float*)d_in[11];
  const float* g2p = (const float*)d_in[12];
  const float* be2p= (const float*)d_in[13];
  const float* W3p = (const float*)d_in[14];
  const float* b3p = (const float*)d_in[15];
  const float* a3p = (const float*)d_in[16];
  const float* g3p = (const float*)d_in[17];
  const float* be3p= (const float*)d_in[18];
  const float* W4p = (const float*)d_in[19];
  const float* b4p = (const float*)d_in[20];
  const float* a4p = (const float*)d_in[21];
  const float* g4p = (const float*)d_in[22];
  const float* be4p= (const float*)d_in[23];
  const float* h1w = (const float*)d_in[24];
  const float* h1b = (const float*)d_in[25];
  const float* h2w = (const float*)d_in[26];
  const float* h2b = (const float*)d_in[27];
  const float* h3w = (const float*)d_in[28];
  const float* h3b = (const float*)d_in[29];

  const int N = in_sizes[0] / 3;
  const int E = in_sizes[3] / 2;
  const int* src = ei;
  const int* dst = ei + E;

  char* p = (char*)d_ws;
  auto alloc = [&](size_t bytes) -> void* {
    void* r = (void*)p;
    p += (bytes + 255) & ~(size_t)255;
    return r;
  };
  float* dis    = (float*)alloc((size_t)N * 4);
  int*   rowptr = (int*)  alloc((size_t)(N + 1) * 4);
  int*   cntA   = (int*)  alloc((size_t)N * 4);
  int*   cntB   = (int*)  alloc((size_t)N * 4);
  int*   bsums  = (int*)  alloc(4096 * 4);
  int*   srcS   = (int*)  alloc((size_t)E * 4);
  float* wS     = (float*)alloc((size_t)E * 4);
  float* bufH   = (float*)alloc((size_t)N * 64 * 4);
  float* bufT1  = (float*)alloc((size_t)N * 64 * 4);
  float* bufT2  = (float*)alloc((size_t)N * 64 * 4);
  float* bufH16 = (float*)alloc((size_t)N * 16 * 4);
  const int MMB = 768;                         // mm blocks (256 thr, 3/CU via 48KB LDS)
  float* bp     = (float*)alloc((size_t)MMB * 128 * 4);
  float* stats  = (float*)alloc(256 * 4);

  hipMemsetAsync(cntA, 0, (size_t)N * 4, stream);
  hipMemsetAsync(cntB, 0, (size_t)N * 4, stream);
  int gE = (E + 255) / 256, gN = (N + 255) / 256;
  hist_kernel<<<gE, 256, 0, stream>>>(src, dst, E, cntA, cntB);
  dis_kernel<<<gN, 256, 0, stream>>>(cntA, dis, N);
  scan1_kernel<<<gN, 256, 0, stream>>>(cntB, N, rowptr, bsums);
  scan2_kernel<<<1, 1024, 0, stream>>>(bsums, gN, rowptr, N);
  scan3_kernel<<<gN, 256, 0, stream>>>(rowptr, bsums, N);
  hipMemsetAsync(cntB, 0, (size_t)N * 4, stream);
  scatter_kernel<<<gE, 256, 0, stream>>>(src, dst, E, rowptr, cntB, dis, srcS, wS);
  pack_kernel<<<(N * 16 + 255) / 256, 256, 0, stream>>>(x, pos, nrm, bufH16, N);

  const float invN = 1.f / (float)N;
  int g64 = (N + 3) / 4, g16 = (N + 15) / 16;
  int gNorm64 = (N * 16 + 255) / 256;
  int gNorm32 = (N * 8 + 255) / 256;
  const int ntiles = (N + 127) / 128;

  // layer 1: 9(pad16) -> 64   h=bufH16, out=bufH
  lap16_kernel<<<g16, 256, 0, stream>>>((const float4*)bufH16, (float4*)bufT1, rowptr, srcS, wS, N);
  lap16_kernel<<<g16, 256, 0, stream>>>((const float4*)bufT1, (float4*)bufT2, rowptr, srcS, wS, N);
  mm_kernel<16, 64><<<MMB, 256, 0, stream>>>(bufH16, bufT1, bufT2, bufH, W1p, b1p, a1p, bp, N, 9, ntiles);
  stats_kernel<<<1, 1024, 0, stream>>>(bp, MMB, g1p, be1p, stats, 64, invN);
  norm_kernel<<<gNorm64, 256, 0, stream>>>((float4*)bufH, stats, N * 16, 4, 16);

  // layer 2: 64 -> 64 (in-place on bufH)
  lap64_kernel<<<g64, 256, 0, stream>>>((const float4*)bufH, (float4*)bufT1, rowptr, srcS, wS, N);
  lap64_kernel<<<g64, 256, 0, stream>>>((const float4*)bufT1, (float4*)bufT2, rowptr, srcS, wS, N);
  mm_kernel<64, 64><<<MMB, 256, 0, stream>>>(bufH, bufT1, bufT2, bufH, W2p, b2p, a2p, bp, N, 64, ntiles);
  stats_kernel<<<1, 1024, 0, stream>>>(bp, MMB, g2p, be2p, stats, 64, invN);
  norm_kernel<<<gNorm64, 256, 0, stream>>>((float4*)bufH, stats, N * 16, 4, 16);

  // layer 3: 64 -> 64 (in-place on bufH)
  lap64_kernel<<<g64, 256, 0, stream>>>((const float4*)bufH, (float4*)bufT1, rowptr, srcS, wS, N);
  lap64_kernel<<<g64, 256, 0, stream>>>((const float4*)bufT1, (float4*)bufT2, rowptr, srcS, wS, N);
  mm_kernel<64, 64><<<MMB, 256, 0, stream>>>(bufH, bufT1, bufT2, bufH, W3p, b3p, a3p, bp, N, 64, ntiles);
  stats_kernel<<<1, 1024, 0, stream>>>(bp, MMB, g3p, be3p, stats, 64, invN);
  norm_kernel<<<gNorm64, 256, 0, stream>>>((float4*)bufH, stats, N * 16, 4, 16);

  // layer 4: 64 -> 32 (out in bufH, stride-64 rows, first 32 cols)
  lap64_kernel<<<g64, 256, 0, stream>>>((const float4*)bufH, (float4*)bufT1, rowptr, srcS, wS, N);
  lap64_kernel<<<g64, 256, 0, stream>>>((const float4*)bufT1, (float4*)bufT2, rowptr, srcS, wS, N);
  mm_kernel<64, 32><<<MMB, 256, 0, stream>>>(bufH, bufT1, bufT2, bufH, W4p, b4p, a4p, bp, N, 64, ntiles);
  stats_kernel<<<1, 1024, 0, stream>>>(bp, MMB, g4p, be4p, stats, 32, invN);
  norm_kernel<<<gNorm32, 256, 0, stream>>>((float4*)bufH, stats, N * 8, 3, 16);

  // final MLP
  mlp_kernel<<<(N + 7) / 8, 256, 0, stream>>>(bufH, h1w, h1b, h2w, h2b, h3w, h3b, (float*)d_out, N);
}

// Round 5
// 1262.034 us; speedup vs baseline: 3.4339x; 1.2057x over previous
//
#include <hip/hip_runtime.h>

constexpr float BN_EPS = 1e-5f;

__device__ __forceinline__ float bf2f(unsigned short u) {
  return __uint_as_float(((unsigned)u) << 16);
}
__device__ __forceinline__ unsigned short f2bf(float f) {
  union { float f; unsigned u; } v; v.f = f;
  unsigned r = v.u + 0x7FFF + ((v.u >> 16) & 1);   // RNE
  return (unsigned short)(r >> 16);
}

// ---------------- graph preprocessing ----------------

__global__ void hist_kernel(const int* __restrict__ src, const int* __restrict__ dst, int E,
                            int* __restrict__ cntA, int* __restrict__ cntB) {
  int e = blockIdx.x * blockDim.x + threadIdx.x;
  if (e < E) {
    atomicAdd(&cntA[src[e]], 1);
    atomicAdd(&cntB[dst[e]], 1);
  }
}

__global__ void dis_kernel(const int* __restrict__ cnt, float* __restrict__ dis, int N) {
  int n = blockIdx.x * blockDim.x + threadIdx.x;
  if (n < N) dis[n] = cnt[n] > 0 ? rsqrtf((float)cnt[n]) : 0.f;
}

__global__ void scan1_kernel(const int* __restrict__ cnt, int N,
                             int* __restrict__ rowptr, int* __restrict__ bsums) {
  int tid = threadIdx.x, lane = tid & 63, wid = tid >> 6;
  int i = blockIdx.x * 256 + tid;
  int v = (i < N) ? cnt[i] : 0;
  int incl = v;
#pragma unroll
  for (int off = 1; off < 64; off <<= 1) {
    int u = __shfl_up(incl, off);
    if (lane >= off) incl += u;
  }
  __shared__ int wt[4];
  if (lane == 63) wt[wid] = incl;
  __syncthreads();
  int woff = 0;
  for (int w = 0; w < wid; ++w) woff += wt[w];
  if (i < N) rowptr[i] = woff + incl - v;
  if (tid == 255) bsums[blockIdx.x] = woff + incl;
}

__global__ void scan2_kernel(int* __restrict__ bsums, int NB, int* __restrict__ rowptr, int N) {
  int tid = threadIdx.x, lane = tid & 63, wid = tid >> 6;
  int v = (tid < NB) ? bsums[tid] : 0;
  int incl = v;
#pragma unroll
  for (int off = 1; off < 64; off <<= 1) {
    int u = __shfl_up(incl, off);
    if (lane >= off) incl += u;
  }
  __shared__ int wt[16];
  if (lane == 63) wt[wid] = incl;
  __syncthreads();
  int woff = 0;
  for (int w = 0; w < wid; ++w) woff += wt[w];
  if (tid < NB) bsums[tid] = woff + incl - v;
  if (tid == blockDim.x - 1) rowptr[N] = woff + incl;
}

__global__ void scan3_kernel(int* __restrict__ rowptr, const int* __restrict__ bsums, int N) {
  int i = blockIdx.x * 256 + threadIdx.x;
  if (i < N) rowptr[i] += bsums[blockIdx.x];
}

__global__ void scatter_kernel(const int* __restrict__ src, const int* __restrict__ dst, int E,
                               const int* __restrict__ rowptr, int* __restrict__ cursor,
                               const float* __restrict__ dis, int2* __restrict__ pk) {
  int e = blockIdx.x * blockDim.x + threadIdx.x;
  if (e < E) {
    int s = src[e], d = dst[e];
    int p = rowptr[d] + atomicAdd(&cursor[d], 1);
    pk[p] = make_int2(s, __float_as_int(-dis[s] * dis[d]));
  }
}

__global__ void pack_kernel(const float* __restrict__ x, const float* __restrict__ pos,
                            const float* __restrict__ nrm, float* __restrict__ h0, int N) {
  int idx = blockIdx.x * blockDim.x + threadIdx.x;
  if (idx < N * 16) {
    int n = idx >> 4, c = idx & 15;
    float v = 0.f;
    if (c < 3) v = x[n * 3 + c];
    else if (c < 6) v = pos[n * 3 + c - 3];
    else if (c < 9) v = nrm[n * 3 + c - 6];
    h0[idx] = v;
  }
}

// ---------------- lap64: gather bf16 rows, fp32 accumulate ----------------
// 1 node per wave; lanes = 4 edge-slots x 16 (ushort4 = 4 bf16 features each).
// AFFINE: out = lap(v)*s + wsum*t (folds the previous layer's BN into this lap).
// WBF16: also write a bf16 mirror of the output (for the next gather).

template <bool AFFINE, bool WBF16>
__global__ __launch_bounds__(256) void lap64_kernel(
    const ushort4* __restrict__ vb, float4* __restrict__ out, ushort4* __restrict__ outb,
    const int* __restrict__ rowptr, const int2* __restrict__ pk,
    const float* __restrict__ st, int N) {
  int tid = threadIdx.x, lane = tid & 63, wid = tid >> 6;
  int node = blockIdx.x * 4 + wid;
  if (node >= N) return;
  int g = lane >> 4, q = lane & 15;
  int r0 = rowptr[node], r1 = rowptr[node + 1];
  float4 a = {0.f, 0.f, 0.f, 0.f}, b = {0.f, 0.f, 0.f, 0.f};
  float ws = 0.f, ws2 = 0.f;
  int k = r0 + g;
  for (; k + 4 < r1; k += 8) {
    int2 p0 = pk[k], p1 = pk[k + 4];
    ushort4 u0 = vb[(size_t)p0.x * 16 + q];
    ushort4 u1 = vb[(size_t)p1.x * 16 + q];
    float w0 = __int_as_float(p0.y), w1 = __int_as_float(p1.y);
    ws += w0; ws2 += w1;
    a.x = fmaf(w0, bf2f(u0.x), a.x); a.y = fmaf(w0, bf2f(u0.y), a.y);
    a.z = fmaf(w0, bf2f(u0.z), a.z); a.w = fmaf(w0, bf2f(u0.w), a.w);
    b.x = fmaf(w1, bf2f(u1.x), b.x); b.y = fmaf(w1, bf2f(u1.y), b.y);
    b.z = fmaf(w1, bf2f(u1.z), b.z); b.w = fmaf(w1, bf2f(u1.w), b.w);
  }
  if (k < r1) {
    int2 p0 = pk[k];
    ushort4 u0 = vb[(size_t)p0.x * 16 + q];
    float w0 = __int_as_float(p0.y);
    ws += w0;
    a.x = fmaf(w0, bf2f(u0.x), a.x); a.y = fmaf(w0, bf2f(u0.y), a.y);
    a.z = fmaf(w0, bf2f(u0.z), a.z); a.w = fmaf(w0, bf2f(u0.w), a.w);
  }
  a.x += b.x; a.y += b.y; a.z += b.z; a.w += b.w; ws += ws2;
  a.x += __shfl_xor(a.x, 16); a.y += __shfl_xor(a.y, 16);
  a.z += __shfl_xor(a.z, 16); a.w += __shfl_xor(a.w, 16);
  ws += __shfl_xor(ws, 16);
  a.x += __shfl_xor(a.x, 32); a.y += __shfl_xor(a.y, 32);
  a.z += __shfl_xor(a.z, 32); a.w += __shfl_xor(a.w, 32);
  ws += __shfl_xor(ws, 32);
  if (g == 0) {
    float4 o = a;
    if (AFFINE) {
      float4 s4 = *(const float4*)(st + q * 4);
      float4 t4 = *(const float4*)(st + 64 + q * 4);
      o.x = fmaf(a.x, s4.x, ws * t4.x);
      o.y = fmaf(a.y, s4.y, ws * t4.y);
      o.z = fmaf(a.z, s4.z, ws * t4.z);
      o.w = fmaf(a.w, s4.w, ws * t4.w);
    }
    out[(size_t)node * 16 + q] = o;
    if constexpr (WBF16) {
      ushort4 ub;
      ub.x = f2bf(o.x); ub.y = f2bf(o.y); ub.z = f2bf(o.z); ub.w = f2bf(o.w);
      outb[(size_t)node * 16 + q] = ub;
    }
  }
}

// lap16: fp32 gather, 4 nodes per wave (layer-1, 16-wide rows)

__global__ __launch_bounds__(256) void lap16_kernel(const float4* __restrict__ v, float4* __restrict__ out,
                                                    const int* __restrict__ rowptr,
                                                    const int2* __restrict__ pk, int N) {
  int tid = threadIdx.x, lane = tid & 63, wid = tid >> 6;
  int node = (blockIdx.x * 4 + wid) * 4 + (lane >> 4);
  int sub = lane & 15, g = sub >> 2, q = sub & 3;
  float4 acc = {0.f, 0.f, 0.f, 0.f};
  if (node < N) {
    int r0 = rowptr[node], r1 = rowptr[node + 1];
    for (int k = r0 + g; k < r1; k += 4) {
      int2 pr = pk[k];
      float w = __int_as_float(pr.y);
      float4 t = v[(size_t)pr.x * 4 + q];
      acc.x = fmaf(w, t.x, acc.x); acc.y = fmaf(w, t.y, acc.y);
      acc.z = fmaf(w, t.z, acc.z); acc.w = fmaf(w, t.w, acc.w);
    }
  }
  acc.x += __shfl_xor(acc.x, 4); acc.y += __shfl_xor(acc.y, 4);
  acc.z += __shfl_xor(acc.z, 4); acc.w += __shfl_xor(acc.w, 4);
  acc.x += __shfl_xor(acc.x, 8); acc.y += __shfl_xor(acc.y, 8);
  acc.z += __shfl_xor(acc.z, 8); acc.w += __shfl_xor(acc.w, 8);
  if (node < N && g == 0) out[(size_t)node * 4 + q] = acc;
}

// ---------------- register-tiled GEMM mm ----------------
// C = [h_n|t1|t2] @ [W0-W2; W1; 2*W2] + b, PReLU, BN partials.
// NORMH: h_n = h*s + t applied at A-load (folds previous layer's BN).
// WBF16: write bf16 mirror of output rows (next layer's gather source).

template <int F_IN, int F_OUT, bool NORMH, bool WBF16>
__global__ __launch_bounds__(256) void mm_kernel(
    const float* h, const float* t1, const float* t2,
    float* out, ushort* outb,
    const float* __restrict__ W, const float* __restrict__ bias,
    const float* __restrict__ aP, const float* __restrict__ stPrev,
    float* __restrict__ bp, int N, int f_in_real, int ntiles) {
  constexpr int CPT = (F_OUT == 64) ? 8 : 4;
  constexpr int WSZ = 3 * F_IN * F_OUT;
  constexpr int RSZ = 32 * F_OUT * 2;
  constexpr int SM = (WSZ > RSZ) ? WSZ : RSZ;
  __shared__ float sm[SM];
  __shared__ float smS[F_IN], smT[F_IN];

  int tid = threadIdx.x;
  const int S = f_in_real * F_OUT;
  for (int idx = tid; idx < WSZ; idx += 256) {
    int m = idx / (F_IN * F_OUT);
    int r = idx - m * (F_IN * F_OUT);
    int i = r / F_OUT, c = r - i * F_OUT;
    float v = 0.f;
    if (i < f_in_real) {
      int b = i * F_OUT + c;
      if (m == 0)      v = W[b] - W[2 * S + b];
      else if (m == 1) v = W[S + b];
      else             v = 2.f * W[2 * S + b];
    }
    sm[idx] = v;
  }
  if (NORMH && tid < F_IN) { smS[tid] = stPrev[tid]; smT[tid] = stPrev[64 + tid]; }
  __syncthreads();

  const int cg = tid & 7;
  const int ngt = tid >> 3;
  const int c0 = cg * CPT;
  const float alpha = aP[0];
  float bb[CPT];
#pragma unroll
  for (int c = 0; c < CPT; ++c) bb[c] = bias[c0 + c];

  float ssum[CPT], ssq[CPT];
#pragma unroll
  for (int c = 0; c < CPT; ++c) { ssum[c] = 0.f; ssq[c] = 0.f; }

  for (int tile = blockIdx.x; tile < ntiles; tile += gridDim.x) {
    const int node0 = tile * 128 + ngt * 4;
    float acc[4][CPT];
#pragma unroll
    for (int j = 0; j < 4; ++j)
#pragma unroll
      for (int c = 0; c < CPT; ++c) acc[j][c] = 0.f;

    const float* As[3] = {h + (size_t)node0 * F_IN, t1 + (size_t)node0 * F_IN, t2 + (size_t)node0 * F_IN};
#pragma unroll
    for (int m = 0; m < 3; ++m) {
      const float* A = As[m];
      const float* Bm = sm + m * F_IN * F_OUT;
#pragma unroll 2
      for (int kb = 0; kb < F_IN / 4; ++kb) {
        float ar[4][4];
#pragma unroll
        for (int j = 0; j < 4; ++j)
          *(float4*)ar[j] = *(const float4*)(A + j * F_IN + kb * 4);
        if (NORMH && m == 0) {
          float4 sv = *(const float4*)(smS + kb * 4);
          float4 tv = *(const float4*)(smT + kb * 4);
#pragma unroll
          for (int j = 0; j < 4; ++j) {
            ar[j][0] = fmaf(ar[j][0], sv.x, tv.x);
            ar[j][1] = fmaf(ar[j][1], sv.y, tv.y);
            ar[j][2] = fmaf(ar[j][2], sv.z, tv.z);
            ar[j][3] = fmaf(ar[j][3], sv.w, tv.w);
          }
        }
#pragma unroll
        for (int kk = 0; kk < 4; ++kk) {
          const float* Brow = Bm + (kb * 4 + kk) * F_OUT + c0;
          float br[CPT];
          *(float4*)br = *(const float4*)Brow;
          if (CPT == 8) *(float4*)(br + 4) = *(const float4*)(Brow + 4);
#pragma unroll
          for (int j = 0; j < 4; ++j)
#pragma unroll
            for (int c = 0; c < CPT; ++c)
              acc[j][c] = fmaf(ar[j][kk], br[c], acc[j][c]);
        }
      }
    }

#pragma unroll
    for (int j = 0; j < 4; ++j) {
      int node = node0 + j;
      if (node < N) {
        float v[CPT];
#pragma unroll
        for (int c = 0; c < CPT; ++c) {
          float t = acc[j][c] + bb[c];
          t = t > 0.f ? t : alpha * t;
          v[c] = t;
          ssum[c] += t;
          ssq[c] += t * t;
        }
        float* o = out + (size_t)node * 64 + c0;
        *(float4*)o = *(float4*)v;
        if (CPT == 8) *(float4*)(o + 4) = *(float4*)(v + 4);
        if constexpr (WBF16) {
          uint4 ub;
          ub.x = (unsigned)f2bf(v[0]) | ((unsigned)f2bf(v[1]) << 16);
          ub.y = (unsigned)f2bf(v[2]) | ((unsigned)f2bf(v[3]) << 16);
          ub.z = (unsigned)f2bf(v[4]) | ((unsigned)f2bf(v[5]) << 16);
          ub.w = (unsigned)f2bf(v[6]) | ((unsigned)f2bf(v[7]) << 16);
          *(uint4*)(outb + (size_t)node * 64 + c0) = ub;
        }
      }
    }
  }

  __syncthreads();
#pragma unroll
  for (int c = 0; c < CPT; ++c) {
    sm[(ngt * F_OUT + c0 + c) * 2 + 0] = ssum[c];
    sm[(ngt * F_OUT + c0 + c) * 2 + 1] = ssq[c];
  }
  __syncthreads();
  if (tid < 128) {
    int col = tid & 63, stat = tid >> 6;
    float tot = 0.f;
    if (col < F_OUT) {
#pragma unroll 8
      for (int g = 0; g < 32; ++g) tot += sm[(g * F_OUT + col) * 2 + stat];
    }
    bp[(size_t)blockIdx.x * 128 + stat * 64 + col] = tot;
  }
}

// ---------------- BN stats reduce -> per-feature affine (s, t) ----------------

__global__ void stats_kernel(const float* __restrict__ bp, int nb,
                             const float* __restrict__ g, const float* __restrict__ be,
                             float* __restrict__ st, int F_OUT, float invN) {
  __shared__ float red[1024];
  int tid = threadIdx.x;
  int t = tid & 127, c = tid >> 7;
  float s = 0.f;
  for (int w = c; w < nb; w += 8) s += bp[(size_t)w * 128 + t];
  red[tid] = s;
  __syncthreads();
  if (tid < 128) {
    float tot = 0.f;
    for (int cc = 0; cc < 8; ++cc) tot += red[cc * 128 + tid];
    red[tid] = tot;
  }
  __syncthreads();
  if (tid < F_OUT) {
    float sum = red[tid], sq = red[64 + tid];
    float mu = sum * invN;
    float var = sq * invN - mu * mu;
    float sc = g[tid] * rsqrtf(var + BN_EPS);
    st[tid] = sc;
    st[64 + tid] = be[tid] - mu * sc;
  }
}

// ---------------- final MLP (applies layer-4 BN affine at load) ----------------

__global__ __launch_bounds__(256) void mlp_kernel(const float* __restrict__ h,
    const float* __restrict__ st,
    const float* __restrict__ w1, const float* __restrict__ b1,
    const float* __restrict__ w2, const float* __restrict__ b2,
    const float* __restrict__ w3, const float* __restrict__ b3,
    float* __restrict__ out, int N) {
  __shared__ float W1[1024], W2[1024], W3[1024], B1[32], B2[32], B3[32], S4[32], T4[32];
  int tid = threadIdx.x;
  for (int idx = tid; idx < 1024; idx += 256) {
    W1[idx] = w1[idx];
    W2[idx] = w2[idx];
    W3[idx] = w3[idx];
  }
  if (tid < 32) {
    B1[tid] = b1[tid]; B2[tid] = b2[tid]; B3[tid] = b3[tid];
    S4[tid] = st[tid]; T4[tid] = st[64 + tid];
  }
  __syncthreads();
  int j = tid & 31;
  int n = blockIdx.x * 8 + (tid >> 5);
  if (n >= N) return;
  float v = fmaf(h[(size_t)n * 64 + j], S4[j], T4[j]);
  float a1 = B1[j];
#pragma unroll
  for (int i = 0; i < 32; ++i) a1 += __shfl(v, i, 32) * W1[i * 32 + j];
  a1 = fmaxf(a1, 0.f);
  float a2 = B2[j];
#pragma unroll
  for (int i = 0; i < 32; ++i) a2 += __shfl(a1, i, 32) * W2[i * 32 + j];
  a2 = fmaxf(a2, 0.f);
  float a3 = B3[j];
#pragma unroll
  for (int i = 0; i < 32; ++i) a3 += __shfl(a2, i, 32) * W3[i * 32 + j];
  out[(size_t)n * 32 + j] = a3;
}

// ---------------- host ----------------

extern "C" void kernel_launch(void* const* d_in, const int* in_sizes, int n_in,
                              void* d_out, int out_size, void* d_ws, size_t ws_size,
                              hipStream_t stream) {
  const float* x   = (const float*)d_in[0];
  const float* pos = (const float*)d_in[1];
  const float* nrm = (const float*)d_in[2];
  const int*   ei  = (const int*)d_in[3];
  const float* W1p = (const float*)d_in[4];
  const float* b1p = (const float*)d_in[5];
  const float* a1p = (const float*)d_in[6];
  const float* g1p = (const float*)d_in[7];
  const float* be1p= (const float*)d_in[8];
  const float* W2p = (const float*)d_in[9];
  const float* b2p = (const float*)d_in[10];
  const float* a2p = (const float*)d_in[11];
  const float* g2p = (const float*)d_in[12];
  const float* be2p= (const float*)d_in[13];
  const float* W3p = (const float*)d_in[14];
  const float* b3p = (const float*)d_in[15];
  const float* a3p = (const float*)d_in[16];
  const float* g3p = (const float*)d_in[17];
  const float* be3p= (const float*)d_in[18];
  const float* W4p = (const float*)d_in[19];
  const float* b4p = (const float*)d_in[20];
  const float* a4p = (const float*)d_in[21];
  const float* g4p = (const float*)d_in[22];
  const float* be4p= (const float*)d_in[23];
  const float* h1w = (const float*)d_in[24];
  const float* h1b = (const float*)d_in[25];
  const float* h2w = (const float*)d_in[26];
  const float* h2b = (const float*)d_in[27];
  const float* h3w = (const float*)d_in[28];
  const float* h3b = (const float*)d_in[29];

  const int N = in_sizes[0] / 3;
  const int E = in_sizes[3] / 2;
  const int* src = ei;
  const int* dst = ei + E;

  char* p = (char*)d_ws;
  auto alloc = [&](size_t bytes) -> void* {
    void* r = (void*)p;
    p += (bytes + 255) & ~(size_t)255;
    return r;
  };
  float* dis    = (float*)alloc((size_t)N * 4);
  int*   rowptr = (int*)  alloc((size_t)(N + 1) * 4);
  int*   cntA   = (int*)  alloc((size_t)N * 4);
  int*   cntB   = (int*)  alloc((size_t)N * 4);
  int*   bsums  = (int*)  alloc(4096 * 4);
  int2*  pk     = (int2*) alloc((size_t)E * 8);
  float* bufH   = (float*)alloc((size_t)N * 64 * 4);
  float* bufT1  = (float*)alloc((size_t)N * 64 * 4);
  float* bufT2  = (float*)alloc((size_t)N * 64 * 4);
  float* bufH16 = (float*)alloc((size_t)N * 16 * 4);
  ushort* bufHb = (ushort*)alloc((size_t)N * 64 * 2);
  ushort* bufT1b= (ushort*)alloc((size_t)N * 64 * 2);
  const int MMB = 768;
  float* bp     = (float*)alloc((size_t)MMB * 128 * 4);
  float* stats  = (float*)alloc(512 * 4);
  float* st1 = stats, *st2 = stats + 128, *st3 = stats + 256, *st4 = stats + 384;

  hipMemsetAsync(cntA, 0, (size_t)N * 4, stream);
  hipMemsetAsync(cntB, 0, (size_t)N * 4, stream);
  int gE = (E + 255) / 256, gN = (N + 255) / 256;
  hist_kernel<<<gE, 256, 0, stream>>>(src, dst, E, cntA, cntB);
  dis_kernel<<<gN, 256, 0, stream>>>(cntA, dis, N);
  scan1_kernel<<<gN, 256, 0, stream>>>(cntB, N, rowptr, bsums);
  scan2_kernel<<<1, 1024, 0, stream>>>(bsums, gN, rowptr, N);
  scan3_kernel<<<gN, 256, 0, stream>>>(rowptr, bsums, N);
  hipMemsetAsync(cntB, 0, (size_t)N * 4, stream);
  scatter_kernel<<<gE, 256, 0, stream>>>(src, dst, E, rowptr, cntB, dis, pk);
  pack_kernel<<<(N * 16 + 255) / 256, 256, 0, stream>>>(x, pos, nrm, bufH16, N);

  const float invN = 1.f / (float)N;
  int g64 = (N + 3) / 4, g16 = (N + 15) / 16;
  const int ntiles = (N + 127) / 128;

  // layer 1: 9(pad16) -> 64 ; fp32 gathers on 16-wide rows
  lap16_kernel<<<g16, 256, 0, stream>>>((const float4*)bufH16, (float4*)bufT1, rowptr, pk, N);
  lap16_kernel<<<g16, 256, 0, stream>>>((const float4*)bufT1, (float4*)bufT2, rowptr, pk, N);
  mm_kernel<16, 64, false, true><<<MMB, 256, 0, stream>>>(bufH16, bufT1, bufT2, bufH, bufHb,
      W1p, b1p, a1p, nullptr, bp, N, 9, ntiles);
  stats_kernel<<<1, 1024, 0, stream>>>(bp, MMB, g1p, be1p, st1, 64, invN);

  // layer 2
  lap64_kernel<true, true><<<g64, 256, 0, stream>>>((const ushort4*)bufHb, (float4*)bufT1,
      (ushort4*)bufT1b, rowptr, pk, st1, N);
  lap64_kernel<false, false><<<g64, 256, 0, stream>>>((const ushort4*)bufT1b, (float4*)bufT2,
      nullptr, rowptr, pk, nullptr, N);
  mm_kernel<64, 64, true, true><<<MMB, 256, 0, stream>>>(bufH, bufT1, bufT2, bufH, bufHb,
      W2p, b2p, a2p, st1, bp, N, 64, ntiles);
  stats_kernel<<<1, 1024, 0, stream>>>(bp, MMB, g2p, be2p, st2, 64, invN);

  // layer 3
  lap64_kernel<true, true><<<g64, 256, 0, stream>>>((const ushort4*)bufHb, (float4*)bufT1,
      (ushort4*)bufT1b, rowptr, pk, st2, N);
  lap64_kernel<false, false><<<g64, 256, 0, stream>>>((const ushort4*)bufT1b, (float4*)bufT2,
      nullptr, rowptr, pk, nullptr, N);
  mm_kernel<64, 64, true, true><<<MMB, 256, 0, stream>>>(bufH, bufT1, bufT2, bufH, bufHb,
      W3p, b3p, a3p, st2, bp, N, 64, ntiles);
  stats_kernel<<<1, 1024, 0, stream>>>(bp, MMB, g3p, be3p, st3, 64, invN);

  // layer 4: 64 -> 32 (out rows stride 64, first 32 cols)
  lap64_kernel<true, true><<<g64, 256, 0, stream>>>((const ushort4*)bufHb, (float4*)bufT1,
      (ushort4*)bufT1b, rowptr, pk, st3, N);
  lap64_kernel<false, false><<<g64, 256, 0, stream>>>((const ushort4*)bufT1b, (float4*)bufT2,
      nullptr, rowptr, pk, nullptr, N);
  mm_kernel<64, 32, true, false><<<MMB, 256, 0, stream>>>(bufH, bufT1, bufT2, bufH, nullptr,
      W4p, b4p, a4p, st3, bp, N, 64, ntiles);
  stats_kernel<<<1, 1024, 0, stream>>>(bp, MMB, g4p, be4p, st4, 32, invN);

  // final MLP (applies st4 affine on load)
  mlp_kernel<<<(N + 7) / 8, 256, 0, stream>>>(bufH, st4, h1w, h1b, h2w, h2b, h3w, h3b,
      (float*)d_out, N);
}

// Round 6
// 1194.325 us; speedup vs baseline: 3.6285x; 1.0567x over previous
//
#include <hip/hip_runtime.h>

constexpr float BN_EPS = 1e-5f;

__device__ __forceinline__ float bf2f(unsigned short u) {
  return __uint_as_float(((unsigned)u) << 16);
}
__device__ __forceinline__ unsigned short f2bf(float f) {
  union { float f; unsigned u; } v; v.f = f;
  unsigned r = v.u + 0x7FFF + ((v.u >> 16) & 1);   // RNE
  return (unsigned short)(r >> 16);
}

// ---------------- graph preprocessing ----------------

// counts out-degree (cntA) and in-degree (cntB); captures each edge's
// within-bucket rank so the scatter pass needs no atomics.
__global__ void hist_kernel(const int* __restrict__ src, const int* __restrict__ dst, int E,
                            int* __restrict__ cntA, int* __restrict__ cntB,
                            ushort* __restrict__ rank16) {
  int e = blockIdx.x * blockDim.x + threadIdx.x;
  if (e < E) {
    atomicAdd(&cntA[src[e]], 1);
    int r = atomicAdd(&cntB[dst[e]], 1);
    rank16[e] = (ushort)r;
  }
}

__global__ void dis_kernel(const int* __restrict__ cnt, float* __restrict__ dis, int N) {
  int n = blockIdx.x * blockDim.x + threadIdx.x;
  if (n < N) dis[n] = cnt[n] > 0 ? rsqrtf((float)cnt[n]) : 0.f;
}

__global__ void scan1_kernel(const int* __restrict__ cnt, int N,
                             int* __restrict__ rowptr, int* __restrict__ bsums) {
  int tid = threadIdx.x, lane = tid & 63, wid = tid >> 6;
  int i = blockIdx.x * 256 + tid;
  int v = (i < N) ? cnt[i] : 0;
  int incl = v;
#pragma unroll
  for (int off = 1; off < 64; off <<= 1) {
    int u = __shfl_up(incl, off);
    if (lane >= off) incl += u;
  }
  __shared__ int wt[4];
  if (lane == 63) wt[wid] = incl;
  __syncthreads();
  int woff = 0;
  for (int w = 0; w < wid; ++w) woff += wt[w];
  if (i < N) rowptr[i] = woff + incl - v;
  if (tid == 255) bsums[blockIdx.x] = woff + incl;
}

__global__ void scan2_kernel(int* __restrict__ bsums, int NB, int* __restrict__ rowptr, int N) {
  int tid = threadIdx.x, lane = tid & 63, wid = tid >> 6;
  int v = (tid < NB) ? bsums[tid] : 0;
  int incl = v;
#pragma unroll
  for (int off = 1; off < 64; off <<= 1) {
    int u = __shfl_up(incl, off);
    if (lane >= off) incl += u;
  }
  __shared__ int wt[16];
  if (lane == 63) wt[wid] = incl;
  __syncthreads();
  int woff = 0;
  for (int w = 0; w < wid; ++w) woff += wt[w];
  if (tid < NB) bsums[tid] = woff + incl - v;
  if (tid == blockDim.x - 1) rowptr[N] = woff + incl;
}

__global__ void scan3_kernel(int* __restrict__ rowptr, const int* __restrict__ bsums, int N) {
  int i = blockIdx.x * 256 + threadIdx.x;
  if (i < N) rowptr[i] += bsums[blockIdx.x];
}

// atomic-free scatter: position = rowptr[dst] + rank
__global__ void scatter_kernel(const int* __restrict__ src, const int* __restrict__ dst, int E,
                               const int* __restrict__ rowptr, const ushort* __restrict__ rank16,
                               const float* __restrict__ dis, int2* __restrict__ pk) {
  int e = blockIdx.x * blockDim.x + threadIdx.x;
  if (e < E) {
    int s = src[e], d = dst[e];
    int p = rowptr[d] + rank16[e];
    pk[p] = make_int2(s, __float_as_int(-dis[s] * dis[d]));
  }
}

__global__ void pack_kernel(const float* __restrict__ x, const float* __restrict__ pos,
                            const float* __restrict__ nrm, float* __restrict__ h0,
                            ushort* __restrict__ h0b, int N) {
  int idx = blockIdx.x * blockDim.x + threadIdx.x;
  if (idx < N * 16) {
    int n = idx >> 4, c = idx & 15;
    float v = 0.f;
    if (c < 3) v = x[n * 3 + c];
    else if (c < 6) v = pos[n * 3 + c - 3];
    else if (c < 9) v = nrm[n * 3 + c - 6];
    h0[idx] = v;
    h0b[idx] = f2bf(v);
  }
}

// ---------------- lap64: bf16 gather -> fp32 accumulate -> bf16 out ----------------
// 1 node per wave; lanes = 4 edge-slots x 16 (ushort4 = 4 bf16 features).
// AFFINE: out = lap(v)*s + wsum*t (folds previous layer's BN).

template <bool AFFINE>
__global__ __launch_bounds__(256) void lap64_kernel(
    const ushort4* __restrict__ vb, ushort4* __restrict__ outb,
    const int* __restrict__ rowptr, const int2* __restrict__ pk,
    const float* __restrict__ st, int N) {
  int tid = threadIdx.x, lane = tid & 63, wid = tid >> 6;
  int node = blockIdx.x * 4 + wid;
  if (node >= N) return;
  int g = lane >> 4, q = lane & 15;
  int r0 = rowptr[node], r1 = rowptr[node + 1];
  float4 a = {0.f, 0.f, 0.f, 0.f}, b = {0.f, 0.f, 0.f, 0.f};
  float ws = 0.f, ws2 = 0.f;
  int k = r0 + g;
  for (; k + 4 < r1; k += 8) {
    int2 p0 = pk[k], p1 = pk[k + 4];
    ushort4 u0 = vb[(size_t)p0.x * 16 + q];
    ushort4 u1 = vb[(size_t)p1.x * 16 + q];
    float w0 = __int_as_float(p0.y), w1 = __int_as_float(p1.y);
    ws += w0; ws2 += w1;
    a.x = fmaf(w0, bf2f(u0.x), a.x); a.y = fmaf(w0, bf2f(u0.y), a.y);
    a.z = fmaf(w0, bf2f(u0.z), a.z); a.w = fmaf(w0, bf2f(u0.w), a.w);
    b.x = fmaf(w1, bf2f(u1.x), b.x); b.y = fmaf(w1, bf2f(u1.y), b.y);
    b.z = fmaf(w1, bf2f(u1.z), b.z); b.w = fmaf(w1, bf2f(u1.w), b.w);
  }
  if (k < r1) {
    int2 p0 = pk[k];
    ushort4 u0 = vb[(size_t)p0.x * 16 + q];
    float w0 = __int_as_float(p0.y);
    ws += w0;
    a.x = fmaf(w0, bf2f(u0.x), a.x); a.y = fmaf(w0, bf2f(u0.y), a.y);
    a.z = fmaf(w0, bf2f(u0.z), a.z); a.w = fmaf(w0, bf2f(u0.w), a.w);
  }
  a.x += b.x; a.y += b.y; a.z += b.z; a.w += b.w; ws += ws2;
  a.x += __shfl_xor(a.x, 16); a.y += __shfl_xor(a.y, 16);
  a.z += __shfl_xor(a.z, 16); a.w += __shfl_xor(a.w, 16);
  ws += __shfl_xor(ws, 16);
  a.x += __shfl_xor(a.x, 32); a.y += __shfl_xor(a.y, 32);
  a.z += __shfl_xor(a.z, 32); a.w += __shfl_xor(a.w, 32);
  ws += __shfl_xor(ws, 32);
  if (g == 0) {
    float4 o = a;
    if (AFFINE) {
      float4 s4 = *(const float4*)(st + q * 4);
      float4 t4 = *(const float4*)(st + 64 + q * 4);
      o.x = fmaf(a.x, s4.x, ws * t4.x);
      o.y = fmaf(a.y, s4.y, ws * t4.y);
      o.z = fmaf(a.z, s4.z, ws * t4.z);
      o.w = fmaf(a.w, s4.w, ws * t4.w);
    }
    ushort4 ub;
    ub.x = f2bf(o.x); ub.y = f2bf(o.y); ub.z = f2bf(o.z); ub.w = f2bf(o.w);
    outb[(size_t)node * 16 + q] = ub;
  }
}

// lap16: bf16 gather, 4 nodes per wave (layer-1, 16-wide rows), bf16 out

__global__ __launch_bounds__(256) void lap16_kernel(const ushort4* __restrict__ vb,
                                                    ushort4* __restrict__ outb,
                                                    const int* __restrict__ rowptr,
                                                    const int2* __restrict__ pk, int N) {
  int tid = threadIdx.x, lane = tid & 63, wid = tid >> 6;
  int node = (blockIdx.x * 4 + wid) * 4 + (lane >> 4);
  int sub = lane & 15, g = sub >> 2, q = sub & 3;
  float4 acc = {0.f, 0.f, 0.f, 0.f};
  if (node < N) {
    int r0 = rowptr[node], r1 = rowptr[node + 1];
    for (int k = r0 + g; k < r1; k += 4) {
      int2 pr = pk[k];
      float w = __int_as_float(pr.y);
      ushort4 u = vb[(size_t)pr.x * 4 + q];
      acc.x = fmaf(w, bf2f(u.x), acc.x); acc.y = fmaf(w, bf2f(u.y), acc.y);
      acc.z = fmaf(w, bf2f(u.z), acc.z); acc.w = fmaf(w, bf2f(u.w), acc.w);
    }
  }
  acc.x += __shfl_xor(acc.x, 4); acc.y += __shfl_xor(acc.y, 4);
  acc.z += __shfl_xor(acc.z, 4); acc.w += __shfl_xor(acc.w, 4);
  acc.x += __shfl_xor(acc.x, 8); acc.y += __shfl_xor(acc.y, 8);
  acc.z += __shfl_xor(acc.z, 8); acc.w += __shfl_xor(acc.w, 8);
  if (node < N && g == 0) {
    ushort4 ub;
    ub.x = f2bf(acc.x); ub.y = f2bf(acc.y); ub.z = f2bf(acc.z); ub.w = f2bf(acc.w);
    outb[(size_t)node * 4 + q] = ub;
  }
}

// ---------------- register-tiled GEMM mm ----------------
// C = [h_n | t1 | t2] @ [W0-W2; W1; 2*W2] + b, PReLU, BN partials.
// h fp32 (NORMH: affine at load); t1/t2 bf16 (converted in-register).
// WBF16: write bf16 mirror of output rows (next layer's gather source).

template <int F_IN, int F_OUT, bool NORMH, bool WBF16>
__global__ __launch_bounds__(256) void mm_kernel(
    const float* h, const ushort* t1b, const ushort* t2b,
    float* out, ushort* outb,
    const float* __restrict__ W, const float* __restrict__ bias,
    const float* __restrict__ aP, const float* __restrict__ stPrev,
    float* __restrict__ bp, int N, int f_in_real, int ntiles) {
  constexpr int CPT = (F_OUT == 64) ? 8 : 4;
  constexpr int WSZ = 3 * F_IN * F_OUT;
  constexpr int RSZ = 32 * F_OUT * 2;
  constexpr int SM = (WSZ > RSZ) ? WSZ : RSZ;
  __shared__ float sm[SM];
  __shared__ float smS[F_IN], smT[F_IN];

  int tid = threadIdx.x;
  const int S = f_in_real * F_OUT;
  for (int idx = tid; idx < WSZ; idx += 256) {
    int m = idx / (F_IN * F_OUT);
    int r = idx - m * (F_IN * F_OUT);
    int i = r / F_OUT, c = r - i * F_OUT;
    float v = 0.f;
    if (i < f_in_real) {
      int b = i * F_OUT + c;
      if (m == 0)      v = W[b] - W[2 * S + b];
      else if (m == 1) v = W[S + b];
      else             v = 2.f * W[2 * S + b];
    }
    sm[idx] = v;
  }
  if (NORMH && tid < F_IN) { smS[tid] = stPrev[tid]; smT[tid] = stPrev[64 + tid]; }
  __syncthreads();

  const int cg = tid & 7;
  const int ngt = tid >> 3;
  const int c0 = cg * CPT;
  const float alpha = aP[0];
  float bb[CPT];
#pragma unroll
  for (int c = 0; c < CPT; ++c) bb[c] = bias[c0 + c];

  float ssum[CPT], ssq[CPT];
#pragma unroll
  for (int c = 0; c < CPT; ++c) { ssum[c] = 0.f; ssq[c] = 0.f; }

  for (int tile = blockIdx.x; tile < ntiles; tile += gridDim.x) {
    const int node0 = tile * 128 + ngt * 4;
    float acc[4][CPT];
#pragma unroll
    for (int j = 0; j < 4; ++j)
#pragma unroll
      for (int c = 0; c < CPT; ++c) acc[j][c] = 0.f;

#pragma unroll
    for (int m = 0; m < 3; ++m) {
      const float* Bm = sm + m * F_IN * F_OUT;
#pragma unroll 2
      for (int kb = 0; kb < F_IN / 4; ++kb) {
        float ar[4][4];
        if (m == 0) {
          const float* A = h + (size_t)node0 * F_IN;
#pragma unroll
          for (int j = 0; j < 4; ++j)
            *(float4*)ar[j] = *(const float4*)(A + j * F_IN + kb * 4);
          if (NORMH) {
            float4 sv = *(const float4*)(smS + kb * 4);
            float4 tv = *(const float4*)(smT + kb * 4);
#pragma unroll
            for (int j = 0; j < 4; ++j) {
              ar[j][0] = fmaf(ar[j][0], sv.x, tv.x);
              ar[j][1] = fmaf(ar[j][1], sv.y, tv.y);
              ar[j][2] = fmaf(ar[j][2], sv.z, tv.z);
              ar[j][3] = fmaf(ar[j][3], sv.w, tv.w);
            }
          }
        } else {
          const ushort* A = (m == 1 ? t1b : t2b) + (size_t)node0 * F_IN;
#pragma unroll
          for (int j = 0; j < 4; ++j) {
            ushort4 u = *(const ushort4*)(A + j * F_IN + kb * 4);
            ar[j][0] = bf2f(u.x); ar[j][1] = bf2f(u.y);
            ar[j][2] = bf2f(u.z); ar[j][3] = bf2f(u.w);
          }
        }
#pragma unroll
        for (int kk = 0; kk < 4; ++kk) {
          const float* Brow = Bm + (kb * 4 + kk) * F_OUT + c0;
          float br[CPT];
          *(float4*)br = *(const float4*)Brow;
          if (CPT == 8) *(float4*)(br + 4) = *(const float4*)(Brow + 4);
#pragma unroll
          for (int j = 0; j < 4; ++j)
#pragma unroll
            for (int c = 0; c < CPT; ++c)
              acc[j][c] = fmaf(ar[j][kk], br[c], acc[j][c]);
        }
      }
    }

#pragma unroll
    for (int j = 0; j < 4; ++j) {
      int node = node0 + j;
      if (node < N) {
        float v[CPT];
#pragma unroll
        for (int c = 0; c < CPT; ++c) {
          float t = acc[j][c] + bb[c];
          t = t > 0.f ? t : alpha * t;
          v[c] = t;
          ssum[c] += t;
          ssq[c] += t * t;
        }
        float* o = out + (size_t)node * 64 + c0;
        *(float4*)o = *(float4*)v;
        if (CPT == 8) *(float4*)(o + 4) = *(float4*)(v + 4);
        if constexpr (WBF16) {
          uint4 ub;
          ub.x = (unsigned)f2bf(v[0]) | ((unsigned)f2bf(v[1]) << 16);
          ub.y = (unsigned)f2bf(v[2]) | ((unsigned)f2bf(v[3]) << 16);
          ub.z = (unsigned)f2bf(v[4]) | ((unsigned)f2bf(v[5]) << 16);
          ub.w = (unsigned)f2bf(v[6]) | ((unsigned)f2bf(v[7]) << 16);
          *(uint4*)(outb + (size_t)node * 64 + c0) = ub;
        }
      }
    }
  }

  __syncthreads();
#pragma unroll
  for (int c = 0; c < CPT; ++c) {
    sm[(ngt * F_OUT + c0 + c) * 2 + 0] = ssum[c];
    sm[(ngt * F_OUT + c0 + c) * 2 + 1] = ssq[c];
  }
  __syncthreads();
  if (tid < 128) {
    int col = tid & 63, stat = tid >> 6;
    float tot = 0.f;
    if (col < F_OUT) {
#pragma unroll 8
      for (int g = 0; g < 32; ++g) tot += sm[(g * F_OUT + col) * 2 + stat];
    }
    bp[(size_t)blockIdx.x * 128 + stat * 64 + col] = tot;
  }
}

// ---------------- BN stats reduce -> per-feature affine (s, t) ----------------

__global__ void stats_kernel(const float* __restrict__ bp, int nb,
                             const float* __restrict__ g, const float* __restrict__ be,
                             float* __restrict__ st, int F_OUT, float invN) {
  __shared__ float red[1024];
  int tid = threadIdx.x;
  int t = tid & 127, c = tid >> 7;
  float s = 0.f;
  for (int w = c; w < nb; w += 8) s += bp[(size_t)w * 128 + t];
  red[tid] = s;
  __syncthreads();
  if (tid < 128) {
    float tot = 0.f;
    for (int cc = 0; cc < 8; ++cc) tot += red[cc * 128 + tid];
    red[tid] = tot;
  }
  __syncthreads();
  if (tid < F_OUT) {
    float sum = red[tid], sq = red[64 + tid];
    float mu = sum * invN;
    float var = sq * invN - mu * mu;
    float sc = g[tid] * rsqrtf(var + BN_EPS);
    st[tid] = sc;
    st[64 + tid] = be[tid] - mu * sc;
  }
}

// ---------------- final MLP (applies layer-4 BN affine at load) ----------------

__global__ __launch_bounds__(256) void mlp_kernel(const float* __restrict__ h,
    const float* __restrict__ st,
    const float* __restrict__ w1, const float* __restrict__ b1,
    const float* __restrict__ w2, const float* __restrict__ b2,
    const float* __restrict__ w3, const float* __restrict__ b3,
    float* __restrict__ out, int N) {
  __shared__ float W1[1024], W2[1024], W3[1024], B1[32], B2[32], B3[32], S4[32], T4[32];
  int tid = threadIdx.x;
  for (int idx = tid; idx < 1024; idx += 256) {
    W1[idx] = w1[idx];
    W2[idx] = w2[idx];
    W3[idx] = w3[idx];
  }
  if (tid < 32) {
    B1[tid] = b1[tid]; B2[tid] = b2[tid]; B3[tid] = b3[tid];
    S4[tid] = st[tid]; T4[tid] = st[64 + tid];
  }
  __syncthreads();
  int j = tid & 31;
  int n = blockIdx.x * 8 + (tid >> 5);
  if (n >= N) return;
  float v = fmaf(h[(size_t)n * 64 + j], S4[j], T4[j]);
  float a1 = B1[j];
#pragma unroll
  for (int i = 0; i < 32; ++i) a1 += __shfl(v, i, 32) * W1[i * 32 + j];
  a1 = fmaxf(a1, 0.f);
  float a2 = B2[j];
#pragma unroll
  for (int i = 0; i < 32; ++i) a2 += __shfl(a1, i, 32) * W2[i * 32 + j];
  a2 = fmaxf(a2, 0.f);
  float a3 = B3[j];
#pragma unroll
  for (int i = 0; i < 32; ++i) a3 += __shfl(a2, i, 32) * W3[i * 32 + j];
  out[(size_t)n * 32 + j] = a3;
}

// ---------------- host ----------------

extern "C" void kernel_launch(void* const* d_in, const int* in_sizes, int n_in,
                              void* d_out, int out_size, void* d_ws, size_t ws_size,
                              hipStream_t stream) {
  const float* x   = (const float*)d_in[0];
  const float* pos = (const float*)d_in[1];
  const float* nrm = (const float*)d_in[2];
  const int*   ei  = (const int*)d_in[3];
  const float* W1p = (const float*)d_in[4];
  const float* b1p = (const float*)d_in[5];
  const float* a1p = (const float*)d_in[6];
  const float* g1p = (const float*)d_in[7];
  const float* be1p= (const float*)d_in[8];
  const float* W2p = (const float*)d_in[9];
  const float* b2p = (const float*)d_in[10];
  const float* a2p = (const float*)d_in[11];
  const float* g2p = (const float*)d_in[12];
  const float* be2p= (const float*)d_in[13];
  const float* W3p = (const float*)d_in[14];
  const float* b3p = (const float*)d_in[15];
  const float* a3p = (const float*)d_in[16];
  const float* g3p = (const float*)d_in[17];
  const float* be3p= (const float*)d_in[18];
  const float* W4p = (const float*)d_in[19];
  const float* b4p = (const float*)d_in[20];
  const float* a4p = (const float*)d_in[21];
  const float* g4p = (const float*)d_in[22];
  const float* be4p= (const float*)d_in[23];
  const float* h1w = (const float*)d_in[24];
  const float* h1b = (const float*)d_in[25];
  const float* h2w = (const float*)d_in[26];
  const float* h2b = (const float*)d_in[27];
  const float* h3w = (const float*)d_in[28];
  const float* h3b = (const float*)d_in[29];

  const int N = in_sizes[0] / 3;
  const int E = in_sizes[3] / 2;
  const int* src = ei;
  const int* dst = ei + E;

  char* p = (char*)d_ws;
  auto alloc = [&](size_t bytes) -> void* {
    void* r = (void*)p;
    p += (bytes + 255) & ~(size_t)255;
    return r;
  };
  float*  dis     = (float*) alloc((size_t)N * 4);
  int*    rowptr  = (int*)   alloc((size_t)(N + 1) * 4);
  int*    cntA    = (int*)   alloc((size_t)N * 4);
  int*    cntB    = (int*)   alloc((size_t)N * 4);
  int*    bsums   = (int*)   alloc(4096 * 4);
  ushort* rank16  = (ushort*)alloc((size_t)E * 2);
  int2*   pk      = (int2*)  alloc((size_t)E * 8);
  float*  bufH    = (float*) alloc((size_t)N * 64 * 4);
  ushort* bufHb   = (ushort*)alloc((size_t)N * 64 * 2);
  ushort* bufT1b  = (ushort*)alloc((size_t)N * 64 * 2);
  ushort* bufT2b  = (ushort*)alloc((size_t)N * 64 * 2);
  float*  bufH16  = (float*) alloc((size_t)N * 16 * 4);
  ushort* bufH16b = (ushort*)alloc((size_t)N * 16 * 2);
  ushort* bufT116b= (ushort*)alloc((size_t)N * 16 * 2);
  ushort* bufT216b= (ushort*)alloc((size_t)N * 16 * 2);
  const int MMB = 768;
  float*  bp      = (float*) alloc((size_t)MMB * 128 * 4);
  float*  stats   = (float*) alloc(512 * 4);
  float* st1 = stats, *st2 = stats + 128, *st3 = stats + 256, *st4 = stats + 384;

  hipMemsetAsync(cntA, 0, (size_t)N * 4, stream);
  hipMemsetAsync(cntB, 0, (size_t)N * 4, stream);
  int gE = (E + 255) / 256, gN = (N + 255) / 256;
  hist_kernel<<<gE, 256, 0, stream>>>(src, dst, E, cntA, cntB, rank16);
  dis_kernel<<<gN, 256, 0, stream>>>(cntA, dis, N);
  scan1_kernel<<<gN, 256, 0, stream>>>(cntB, N, rowptr, bsums);
  scan2_kernel<<<1, 1024, 0, stream>>>(bsums, gN, rowptr, N);
  scan3_kernel<<<gN, 256, 0, stream>>>(rowptr, bsums, N);
  scatter_kernel<<<gE, 256, 0, stream>>>(src, dst, E, rowptr, rank16, dis, pk);
  pack_kernel<<<(N * 16 + 255) / 256, 256, 0, stream>>>(x, pos, nrm, bufH16, bufH16b, N);

  const float invN = 1.f / (float)N;
  int g64 = (N + 3) / 4, g16 = (N + 15) / 16;
  const int ntiles = (N + 127) / 128;

  // layer 1: 9(pad16) -> 64 ; bf16 gathers on 16-wide rows
  lap16_kernel<<<g16, 256, 0, stream>>>((const ushort4*)bufH16b, (ushort4*)bufT116b, rowptr, pk, N);
  lap16_kernel<<<g16, 256, 0, stream>>>((const ushort4*)bufT116b, (ushort4*)bufT216b, rowptr, pk, N);
  mm_kernel<16, 64, false, true><<<MMB, 256, 0, stream>>>(bufH16, bufT116b, bufT216b, bufH, bufHb,
      W1p, b1p, a1p, nullptr, bp, N, 9, ntiles);
  stats_kernel<<<1, 1024, 0, stream>>>(bp, MMB, g1p, be1p, st1, 64, invN);

  // layer 2
  lap64_kernel<true><<<g64, 256, 0, stream>>>((const ushort4*)bufHb, (ushort4*)bufT1b,
      rowptr, pk, st1, N);
  lap64_kernel<false><<<g64, 256, 0, stream>>>((const ushort4*)bufT1b, (ushort4*)bufT2b,
      rowptr, pk, nullptr, N);
  mm_kernel<64, 64, true, true><<<MMB, 256, 0, stream>>>(bufH, bufT1b, bufT2b, bufH, bufHb,
      W2p, b2p, a2p, st1, bp, N, 64, ntiles);
  stats_kernel<<<1, 1024, 0, stream>>>(bp, MMB, g2p, be2p, st2, 64, invN);

  // layer 3
  lap64_kernel<true><<<g64, 256, 0, stream>>>((const ushort4*)bufHb, (ushort4*)bufT1b,
      rowptr, pk, st2, N);
  lap64_kernel<false><<<g64, 256, 0, stream>>>((const ushort4*)bufT1b, (ushort4*)bufT2b,
      rowptr, pk, nullptr, N);
  mm_kernel<64, 64, true, true><<<MMB, 256, 0, stream>>>(bufH, bufT1b, bufT2b, bufH, bufHb,
      W3p, b3p, a3p, st2, bp, N, 64, ntiles);
  stats_kernel<<<1, 1024, 0, stream>>>(bp, MMB, g3p, be3p, st3, 64, invN);

  // layer 4: 64 -> 32 (out rows stride 64, first 32 cols)
  lap64_kernel<true><<<g64, 256, 0, stream>>>((const ushort4*)bufHb, (ushort4*)bufT1b,
      rowptr, pk, st3, N);
  lap64_kernel<false><<<g64, 256, 0, stream>>>((const ushort4*)bufT1b, (ushort4*)bufT2b,
      rowptr, pk, nullptr, N);
  mm_kernel<64, 32, true, false><<<MMB, 256, 0, stream>>>(bufH, bufT1b, bufT2b, bufH, nullptr,
      W4p, b4p, a4p, st3, bp, N, 64, ntiles);
  stats_kernel<<<1, 1024, 0, stream>>>(bp, MMB, g4p, be4p, st4, 32, invN);

  // final MLP (applies st4 affine on load)
  mlp_kernel<<<(N + 7) / 8, 256, 0, stream>>>(bufH, st4, h1w, h1b, h2w, h2b, h3w, h3b,
      (float*)d_out, N);
}